// Round 1
// baseline (2760.703 us; speedup 1.0000x reference)
//
#include <hip/hip_runtime.h>
#include <hip/hip_bf16.h>
#include <math.h>

#define B_    2
#define CIN   512
#define S_    1024
#define D_    768
#define NH    12
#define HD_   64
#define E_    8
#define FF_   2048
#define T_    2048
#define FBINS 513
#define NS2   1026
#define KPAD  1056              // NS2 padded to mult of 32
#define NPADO 1152              // NS2 padded to mult of 128
#define WIN_  1024
#define HOP_  256
#define PAD_  384
#define OUTP  262144
#define AGR   4224              // 2T + 128 pad rows

static inline int cdiv(int a, int b) { return (a + b - 1) / b; }

typedef _Float16 half8 __attribute__((ext_vector_type(8)));
typedef __attribute__((ext_vector_type(4))) float floatx4;

#define MFMA16(a, b, c) __builtin_amdgcn_mfma_f32_16x16x32_f16(a, b, c, 0, 0, 0)
#define LO_SCALE 2048.0f
#define LO_INV   (1.0f / 2048.0f)

// split fp32 -> (hi fp16, lo fp16 scaled by 2048); planes are short-typed
__device__ inline void split_store(float v, short* p, size_t planeOff) {
    _Float16 h = (_Float16)v;
    _Float16 l = (_Float16)((v - (float)h) * LO_SCALE);
    *(_Float16*)p = h;
    *(_Float16*)(p + planeOff) = l;
}

__device__ inline float gelu_f(float x) {
    float x3 = x * x * x;
    return 0.5f * x * (1.0f + tanhf(0.7978845608028654f * (x + 0.044715f * x3)));
}

__device__ inline void gl_lds16(const short* g, short* l) {
    __builtin_amdgcn_global_load_lds((const __attribute__((address_space(1))) void*)g,
                                     (__attribute__((address_space(3))) void*)l, 16, 0, 0);
}

// ===== split-fp16 MFMA GEMM core (128x128 tile, BK=32, 3 MFMAs per frag pair) =====
// MODE 0: f32 store; 1: f32 +=; 2: split-pair store; 3: gelu -> split-pair store
template <int MODE>
__global__ __launch_bounds__(256) void mm2_k(
    const short* __restrict__ Ah, const short* __restrict__ Al,
    const short* __restrict__ Bh, const short* __restrict__ Bl,
    const float* __restrict__ bias, float* __restrict__ Cf,
    short* __restrict__ Cp, size_t CpPl,
    int Nstore, int K, int SA, int SB, int SC) {
    __shared__ short AsH[4096], AsL[4096], BsH[4096], BsL[4096];
    int tid = threadIdx.x;
    int wave = tid >> 6, lane = tid & 63;
    int m0 = blockIdx.y * 128, n0 = blockIdx.x * 128;
    int wm = (wave & 1) * 64, wn = (wave >> 1) * 64;
    floatx4 a1[4][4], a2[4][4];
#pragma unroll
    for (int i = 0; i < 4; ++i)
#pragma unroll
        for (int j = 0; j < 4; ++j) {
            a1[i][j] = (floatx4){0.f, 0.f, 0.f, 0.f};
            a2[i][j] = (floatx4){0.f, 0.f, 0.f, 0.f};
        }
    int lm = lane & 15, lk = (lane >> 4) * 8;
    int fl0 = wave * 64 + lane, fl1 = fl0 + 256;
    int r0 = fl0 >> 2, c0 = (fl0 & 3) * 8;
    int r1 = fl1 >> 2, c1 = (fl1 & 3) * 8;
    int kIters = K >> 5;
    for (int kt = 0; kt < kIters; ++kt) {
        int k0 = kt << 5;
        size_t a0 = (size_t)(m0 + r0) * SA + k0 + c0;
        size_t a1o = (size_t)(m0 + r1) * SA + k0 + c1;
        size_t b0 = (size_t)(n0 + r0) * SB + k0 + c0;
        size_t b1 = (size_t)(n0 + r1) * SB + k0 + c1;
        gl_lds16(Ah + a0, AsH + wave * 512);
        gl_lds16(Ah + a1o, AsH + (wave + 4) * 512);
        gl_lds16(Al + a0, AsL + wave * 512);
        gl_lds16(Al + a1o, AsL + (wave + 4) * 512);
        gl_lds16(Bh + b0, BsH + wave * 512);
        gl_lds16(Bh + b1, BsH + (wave + 4) * 512);
        gl_lds16(Bl + b0, BsL + wave * 512);
        gl_lds16(Bl + b1, BsL + (wave + 4) * 512);
        __syncthreads();
        half8 ah[4], al[4], bh[4], bl[4];
#pragma unroll
        for (int i = 0; i < 4; ++i) {
            int off = (wm + i * 16 + lm) * 32 + lk;
            ah[i] = *(const half8*)(AsH + off);
            al[i] = *(const half8*)(AsL + off);
        }
#pragma unroll
        for (int j = 0; j < 4; ++j) {
            int off = (wn + j * 16 + lm) * 32 + lk;
            bh[j] = *(const half8*)(BsH + off);
            bl[j] = *(const half8*)(BsL + off);
        }
#pragma unroll
        for (int i = 0; i < 4; ++i)
#pragma unroll
            for (int j = 0; j < 4; ++j) {
                a1[i][j] = MFMA16(ah[i], bh[j], a1[i][j]);
                a2[i][j] = MFMA16(ah[i], bl[j], a2[i][j]);
                a2[i][j] = MFMA16(al[i], bh[j], a2[i][j]);
            }
        __syncthreads();
    }
    int row4 = (lane >> 4) * 4;
#pragma unroll
    for (int i = 0; i < 4; ++i) {
        int row = m0 + wm + i * 16 + row4;
#pragma unroll
        for (int j = 0; j < 4; ++j) {
            int col = n0 + wn + j * 16 + lm;
            if (col < Nstore) {
                float bv = bias ? bias[col] : 0.0f;
#pragma unroll
                for (int r = 0; r < 4; ++r) {
                    float v = a1[i][j][r] + a2[i][j][r] * LO_INV + bv;
                    size_t idx = (size_t)(row + r) * SC + col;
                    if (MODE == 0) Cf[idx] = v;
                    else if (MODE == 1) Cf[idx] += v;
                    else if (MODE == 2) split_store(v, Cp + idx, CpPl);
                    else split_store(gelu_f(v), Cp + idx, CpPl);
                }
            }
        }
    }
}

// ===== grouped MoE variant over expert row-segments (2 experts per launch) =====
template <int MODE>
__global__ __launch_bounds__(256) void mm2_moe_k(
    const short* __restrict__ Agh, const short* __restrict__ Agl,
    const short* __restrict__ BT, size_t eStride, size_t bPl,
    const float* __restrict__ biasAll, int biasStride,
    float* __restrict__ Cf, short* __restrict__ Cp, size_t CpPl,
    const int* __restrict__ counts, const int* __restrict__ offsets,
    int N, int K, int SA, int SB, int SC) {
    int el = blockIdx.z;
    int nrows = counts[el];
    int m0 = blockIdx.y * 128;
    if (m0 >= nrows) return;
    int base = offsets[el];
    const short* Ah = Agh + (size_t)base * SA;
    const short* Al = Agl + (size_t)base * SA;
    const short* Bh = BT + (size_t)el * eStride;
    const short* Bl = Bh + bPl;
    const float* bias = biasAll + (size_t)el * biasStride;
    __shared__ short AsH[4096], AsL[4096], BsH[4096], BsL[4096];
    int tid = threadIdx.x;
    int wave = tid >> 6, lane = tid & 63;
    int n0 = blockIdx.x * 128;
    int wm = (wave & 1) * 64, wn = (wave >> 1) * 64;
    floatx4 a1[4][4], a2[4][4];
#pragma unroll
    for (int i = 0; i < 4; ++i)
#pragma unroll
        for (int j = 0; j < 4; ++j) {
            a1[i][j] = (floatx4){0.f, 0.f, 0.f, 0.f};
            a2[i][j] = (floatx4){0.f, 0.f, 0.f, 0.f};
        }
    int lm = lane & 15, lk = (lane >> 4) * 8;
    int fl0 = wave * 64 + lane, fl1 = fl0 + 256;
    int r0 = fl0 >> 2, c0 = (fl0 & 3) * 8;
    int r1 = fl1 >> 2, c1 = (fl1 & 3) * 8;
    int kIters = K >> 5;
    for (int kt = 0; kt < kIters; ++kt) {
        int k0 = kt << 5;
        size_t a0 = (size_t)(m0 + r0) * SA + k0 + c0;
        size_t a1o = (size_t)(m0 + r1) * SA + k0 + c1;
        size_t b0 = (size_t)(n0 + r0) * SB + k0 + c0;
        size_t b1 = (size_t)(n0 + r1) * SB + k0 + c1;
        gl_lds16(Ah + a0, AsH + wave * 512);
        gl_lds16(Ah + a1o, AsH + (wave + 4) * 512);
        gl_lds16(Al + a0, AsL + wave * 512);
        gl_lds16(Al + a1o, AsL + (wave + 4) * 512);
        gl_lds16(Bh + b0, BsH + wave * 512);
        gl_lds16(Bh + b1, BsH + (wave + 4) * 512);
        gl_lds16(Bl + b0, BsL + wave * 512);
        gl_lds16(Bl + b1, BsL + (wave + 4) * 512);
        __syncthreads();
        half8 ah[4], al[4], bh[4], bl[4];
#pragma unroll
        for (int i = 0; i < 4; ++i) {
            int off = (wm + i * 16 + lm) * 32 + lk;
            ah[i] = *(const half8*)(AsH + off);
            al[i] = *(const half8*)(AsL + off);
        }
#pragma unroll
        for (int j = 0; j < 4; ++j) {
            int off = (wn + j * 16 + lm) * 32 + lk;
            bh[j] = *(const half8*)(BsH + off);
            bl[j] = *(const half8*)(BsL + off);
        }
#pragma unroll
        for (int i = 0; i < 4; ++i)
#pragma unroll
            for (int j = 0; j < 4; ++j) {
                a1[i][j] = MFMA16(ah[i], bh[j], a1[i][j]);
                a2[i][j] = MFMA16(ah[i], bl[j], a2[i][j]);
                a2[i][j] = MFMA16(al[i], bh[j], a2[i][j]);
            }
        __syncthreads();
    }
    int row4 = (lane >> 4) * 4;
#pragma unroll
    for (int i = 0; i < 4; ++i) {
        int rl = m0 + wm + i * 16 + row4;
#pragma unroll
        for (int j = 0; j < 4; ++j) {
            int col = n0 + wn + j * 16 + lm;
            if (col < N) {
                float bv = bias[col];
#pragma unroll
                for (int r = 0; r < 4; ++r) {
                    if (rl + r < nrows) {
                        float v = a1[i][j][r] + a2[i][j][r] * LO_INV + bv;
                        size_t idx = (size_t)(base + rl + r) * SC + col;
                        if (MODE == 0) Cf[idx] = v;
                        else split_store(gelu_f(v), Cp + idx, CpPl);
                    }
                }
            }
        }
    }
}

// ===== transpose fp32 [Z][R][C] -> split-pair [Z][Cout][R] (zero rows c>=C) =====
__global__ __launch_bounds__(256) void transp2_k(const float* __restrict__ src,
                                                 short* __restrict__ dst, int R, int C, int Cout,
                                                 size_t srcZ, size_t dstZ, size_t planeOff) {
    __shared__ float tile[32][33];
    int z = blockIdx.z;
    src += (size_t)z * srcZ;
    dst += (size_t)z * dstZ;
    int c0 = blockIdx.x * 32, r0 = blockIdx.y * 32;
    int tx = threadIdx.x & 31, ty = threadIdx.x >> 5;
    for (int i = ty; i < 32; i += 8) {
        int r = r0 + i, c = c0 + tx;
        tile[i][tx] = (r < R && c < C) ? src[(size_t)r * C + c] : 0.0f;
    }
    __syncthreads();
    for (int i = ty; i < 32; i += 8) {
        int cc = c0 + i, rr = r0 + tx;
        if (cc < Cout && rr < R) split_store(tile[tx][i], dst + (size_t)cc * R + rr, planeOff);
    }
}

// ===== transpose z: [B,CIN,S] -> zT pair [t][c] =====
__global__ __launch_bounds__(256) void tz2_k(const float* __restrict__ z, short* __restrict__ xT,
                                             size_t planeOff) {
    int id = blockIdx.x * 256 + threadIdx.x;
    if (id >= T_ * CIN) return;
    int t = id >> 9, c = id & 511;
    int b = t >> 10, l = t & 1023;
    split_store(z[((size_t)b * CIN + c) * S_ + l], xT + id, planeOff);
}

// ===== LayerNorm per token -> split pair =====
__global__ __launch_bounds__(256) void ln_k(const float* __restrict__ x,
                                            const float* __restrict__ g,
                                            const float* __restrict__ b, short* __restrict__ h,
                                            size_t planeOff) {
    int t = blockIdx.x;
    int tid = threadIdx.x;
    __shared__ float row[D_];
    __shared__ float red[256];
    const float* xr = x + (size_t)t * D_;
    float s = 0.0f;
    for (int i = tid; i < D_; i += 256) {
        float v = xr[i];
        row[i] = v;
        s += v;
    }
    red[tid] = s;
    __syncthreads();
    for (int st = 128; st > 0; st >>= 1) {
        if (tid < st) red[tid] += red[tid + st];
        __syncthreads();
    }
    float mean = red[0] / (float)D_;
    __syncthreads();
    float s2 = 0.0f;
    for (int i = tid; i < D_; i += 256) {
        float d = row[i] - mean;
        s2 += d * d;
    }
    red[tid] = s2;
    __syncthreads();
    for (int st = 128; st > 0; st >>= 1) {
        if (tid < st) red[tid] += red[tid + st];
        __syncthreads();
    }
    float rstd = rsqrtf(red[0] / (float)D_ + 1e-5f);
    for (int i = tid; i < D_; i += 256)
        split_store((row[i] - mean) * rstd * g[i] + b[i], h + (size_t)t * D_ + i, planeOff);
}

// ===== fused fp32 LN + gating logits =====
__global__ __launch_bounds__(256) void lngate_k(const float* __restrict__ x,
                                                const float* __restrict__ g,
                                                const float* __restrict__ b,
                                                const float* __restrict__ gw,
                                                float* __restrict__ logits) {
    int t = blockIdx.x;
    int tid = threadIdx.x;
    __shared__ float row[D_];
    __shared__ float red[256];
    const float* xr = x + (size_t)t * D_;
    float s = 0.0f;
    for (int i = tid; i < D_; i += 256) {
        float v = xr[i];
        row[i] = v;
        s += v;
    }
    red[tid] = s;
    __syncthreads();
    for (int st = 128; st > 0; st >>= 1) {
        if (tid < st) red[tid] += red[tid + st];
        __syncthreads();
    }
    float mean = red[0] / (float)D_;
    __syncthreads();
    float s2 = 0.0f;
    for (int i = tid; i < D_; i += 256) {
        float d = row[i] - mean;
        s2 += d * d;
    }
    red[tid] = s2;
    __syncthreads();
    for (int st = 128; st > 0; st >>= 1) {
        if (tid < st) red[tid] += red[tid + st];
        __syncthreads();
    }
    float rstd = rsqrtf(red[0] / (float)D_ + 1e-5f);
    __syncthreads();
    int e = tid >> 5, lane = tid & 31;
    float acc = 0.0f;
    for (int d = lane; d < D_; d += 32)
        acc += ((row[d] - mean) * rstd * g[d] + b[d]) * gw[d * E_ + e];
    red[tid] = acc;
    __syncthreads();
    for (int st = 16; st > 0; st >>= 1) {
        if (lane < st) red[tid] += red[tid + st];
        __syncthreads();
    }
    if (lane == 0) logits[t * E_ + e] = red[tid];
}

// ===== RoPE in place (fp32 q/k) =====
__global__ __launch_bounds__(256) void rope_k(float* __restrict__ x) {
    int id = blockIdx.x * 256 + threadIdx.x;
    if (id >= T_ * 384) return;
    int t = id / 384, j = id % 384;
    int pos = t & 1023;
    float inv = expf(-(float)j * (9.210340371976184f / 384.0f));
    float ang = (float)pos * inv;
    float sn, cs;
    sincosf(ang, &sn, &cs);
    float* p = x + (size_t)t * D_ + 2 * j;
    float x1 = p[0], x2 = p[1];
    p[0] = x1 * cs - x2 * sn;
    p[1] = x1 * sn + x2 * cs;
}

// ===== fp32 -> split pair, elementwise (for q, k) =====
__global__ __launch_bounds__(256) void split_k(const float* __restrict__ s,
                                               short* __restrict__ d) {
    int id = blockIdx.x * 256 + threadIdx.x;
    if (id < T_ * D_) split_store(s[id], d + id, (size_t)T_ * D_);
}

// ===== V [T][D] -> V^T pair [BH][64][S] =====
__global__ __launch_bounds__(256) void vt2_k(const float* __restrict__ v,
                                             short* __restrict__ vp) {
    __shared__ float tile[32][33];
    int bh = blockIdx.z, b = bh / NH, h = bh % NH;
    int j0 = blockIdx.x * 32, d0 = blockIdx.y * 32;
    int tx = threadIdx.x & 31, ty = threadIdx.x >> 5;
    for (int i = ty; i < 32; i += 8)
        tile[i][tx] = v[(size_t)(b * S_ + j0 + i) * D_ + h * 64 + d0 + tx];
    __syncthreads();
    for (int i = ty; i < 32; i += 8)
        split_store(tile[tx][i], vp + ((size_t)bh * 64 + d0 + i) * S_ + j0 + tx,
                    (size_t)T_ * D_);
}

// ===== flash attention: split-fp16 MFMA, online softmax, causal =====
// grid (16 q-tiles of 64 rows, 24 bh), block 256 (4 waves x 16 Q-rows)
__global__ __launch_bounds__(256) void fattn_k(const short* __restrict__ qp,
                                               const short* __restrict__ kp,
                                               const short* __restrict__ vp,
                                               short* __restrict__ ctx) {
    __shared__ short sQ[2][64 * 64];
    __shared__ short sK[2][128 * 64];
    __shared__ short sV[2][64 * 128];
    __shared__ short sP[2][4][16 * 128];
    const size_t PL = (size_t)T_ * D_;
    int qt = blockIdx.x, bh = blockIdx.y;
    int b = bh / NH, h = bh % NH;
    int tid = threadIdx.x, wave = tid >> 6, lane = tid & 63;
    int quad = lane >> 4, lm = lane & 15;
    int t0 = b * S_ + qt * 64;
    {   // stage Q: per wave, 2 chunks of 8 rows per plane
        int lr = lane >> 3, lc = (lane & 7) * 8;
#pragma unroll
        for (int pl = 0; pl < 2; ++pl)
#pragma unroll
            for (int c = 0; c < 2; ++c) {
                int r8 = wave * 16 + c * 8;
                gl_lds16(qp + pl * PL + (size_t)(t0 + r8 + lr) * D_ + h * 64 + lc,
                         &sQ[pl][r8 * 64]);
            }
    }
    floatx4 o1[4], o2[4];
#pragma unroll
    for (int n = 0; n < 4; ++n) {
        o1[n] = (floatx4){0.f, 0.f, 0.f, 0.f};
        o2[n] = (floatx4){0.f, 0.f, 0.f, 0.f};
    }
    float mrow[4] = {-1e30f, -1e30f, -1e30f, -1e30f};
    float lrow[4] = {0.f, 0.f, 0.f, 0.f};
    int ktmax = qt >> 1;
    for (int kt = 0; kt <= ktmax; ++kt) {
        {   // stage K: per wave, 4 chunks of 8 rows per plane
            int lr = lane >> 3, lc = (lane & 7) * 8;
#pragma unroll
            for (int pl = 0; pl < 2; ++pl)
#pragma unroll
                for (int c = 0; c < 4; ++c) {
                    int r8 = wave * 32 + c * 8;
                    gl_lds16(kp + pl * PL +
                                 (size_t)(b * S_ + kt * 128 + r8 + lr) * D_ + h * 64 + lc,
                             &sK[pl][r8 * 64]);
                }
            // stage V^T: per wave, 4 chunks of 4 rows (128 shorts) per plane
            int vr = lane >> 4, vc = (lane & 15) * 8;
#pragma unroll
            for (int pl = 0; pl < 2; ++pl)
#pragma unroll
                for (int c = 0; c < 4; ++c) {
                    int r4 = wave * 16 + c * 4;
                    gl_lds16(vp + pl * PL + ((size_t)bh * 64 + r4 + vr) * S_ + kt * 128 + vc,
                             &sV[pl][r4 * 128]);
                }
        }
        __syncthreads();
        // ---- S = Q K^T * scale (split-fp16) ----
        half8 qh[2], ql[2];
#pragma unroll
        for (int ks = 0; ks < 2; ++ks) {
            int off = (wave * 16 + lm) * 64 + ks * 32 + quad * 8;
            qh[ks] = *(const half8*)&sQ[0][off];
            ql[ks] = *(const half8*)&sQ[1][off];
        }
        floatx4 sacc[8];
#pragma unroll
        for (int nt = 0; nt < 8; ++nt) {
            floatx4 c1 = (floatx4){0.f, 0.f, 0.f, 0.f};
            floatx4 c2 = (floatx4){0.f, 0.f, 0.f, 0.f};
#pragma unroll
            for (int ks = 0; ks < 2; ++ks) {
                int off = (nt * 16 + lm) * 64 + ks * 32 + quad * 8;
                half8 kh = *(const half8*)&sK[0][off];
                half8 kl = *(const half8*)&sK[1][off];
                c1 = MFMA16(qh[ks], kh, c1);
                c2 = MFMA16(qh[ks], kl, c2);
                c2 = MFMA16(ql[ks], kh, c2);
            }
#pragma unroll
            for (int r = 0; r < 4; ++r) sacc[nt][r] = (c1[r] + c2[r] * LO_INV) * 0.125f;
        }
        if (kt == ktmax) {  // causal mask on the diagonal tile
#pragma unroll
            for (int nt = 0; nt < 8; ++nt) {
                int col = kt * 128 + nt * 16 + lm;
#pragma unroll
                for (int r = 0; r < 4; ++r) {
                    int rowg = qt * 64 + wave * 16 + quad * 4 + r;
                    if (col > rowg) sacc[nt][r] = -1e30f;
                }
            }
        }
        // ---- online softmax (wave-local; rows live in 16-lane quads) ----
        float mnew[4], al[4], ls[4];
#pragma unroll
        for (int r = 0; r < 4; ++r) {
            float mx = sacc[0][r];
#pragma unroll
            for (int nt = 1; nt < 8; ++nt) mx = fmaxf(mx, sacc[nt][r]);
#pragma unroll
            for (int msk = 1; msk < 16; msk <<= 1) mx = fmaxf(mx, __shfl_xor(mx, msk));
            mnew[r] = fmaxf(mrow[r], mx);
            al[r] = __expf(mrow[r] - mnew[r]);
            mrow[r] = mnew[r];
            ls[r] = 0.f;
        }
#pragma unroll
        for (int nt = 0; nt < 8; ++nt)
#pragma unroll
            for (int r = 0; r < 4; ++r) {
                float p = __expf(sacc[nt][r] - mnew[r]);
                ls[r] += p;
                _Float16 ph = (_Float16)p;
                _Float16 plo = (_Float16)((p - (float)ph) * LO_SCALE);
                int off = (quad * 4 + r) * 128 + nt * 16 + lm;
                *(_Float16*)&sP[0][wave][off] = ph;
                *(_Float16*)&sP[1][wave][off] = plo;
            }
#pragma unroll
        for (int r = 0; r < 4; ++r) {
#pragma unroll
            for (int msk = 1; msk < 16; msk <<= 1) ls[r] += __shfl_xor(ls[r], msk);
            lrow[r] = lrow[r] * al[r] + ls[r];
        }
#pragma unroll
        for (int n = 0; n < 4; ++n)
#pragma unroll
            for (int r = 0; r < 4; ++r) {
                o1[n][r] *= al[r];
                o2[n][r] *= al[r];
            }
        // ---- O += P V (split-fp16; P via per-wave LDS roundtrip) ----
        half8 ph8[4], pl8[4];
#pragma unroll
        for (int ks = 0; ks < 4; ++ks) {
            int off = lm * 128 + ks * 32 + quad * 8;
            ph8[ks] = *(const half8*)&sP[0][wave][off];
            pl8[ks] = *(const half8*)&sP[1][wave][off];
        }
#pragma unroll
        for (int nt2 = 0; nt2 < 4; ++nt2) {
#pragma unroll
            for (int ks = 0; ks < 4; ++ks) {
                int off = (nt2 * 16 + lm) * 128 + ks * 32 + quad * 8;
                half8 vh = *(const half8*)&sV[0][off];
                half8 vl = *(const half8*)&sV[1][off];
                o1[nt2] = MFMA16(ph8[ks], vh, o1[nt2]);
                o2[nt2] = MFMA16(ph8[ks], vl, o2[nt2]);
                o2[nt2] = MFMA16(pl8[ks], vh, o2[nt2]);
            }
        }
        __syncthreads();
    }
    // ---- epilogue: normalize, split-store ctx ----
#pragma unroll
    for (int r = 0; r < 4; ++r) {
        float inv = 1.0f / lrow[r];
        int rowg = t0 + wave * 16 + quad * 4 + r;
#pragma unroll
        for (int nt2 = 0; nt2 < 4; ++nt2) {
            float val = (o1[nt2][r] + o2[nt2][r] * LO_INV) * inv;
            int col = h * 64 + nt2 * 16 + lm;
            split_store(val, ctx + (size_t)rowg * D_ + col, PL);
        }
    }
}

__global__ void zero_meta_k(int* __restrict__ counts) {
    int i = threadIdx.x;
    if (i < E_) counts[i] = 0;
}

__global__ __launch_bounds__(256) void top2_k(const float* __restrict__ logits,
                                              int* __restrict__ counts, int* __restrict__ tokE,
                                              float* __restrict__ tokW) {
    int t = blockIdx.x * 256 + threadIdx.x;
    if (t >= T_) return;
    const float* l = logits + t * E_;
    int i0 = 0;
    float v0 = l[0];
    for (int e = 1; e < E_; ++e) {
        float v = l[e];
        if (v > v0) { v0 = v; i0 = e; }
    }
    int i1 = -1;
    float v1 = -1e30f;
    for (int e = 0; e < E_; ++e) {
        if (e == i0) continue;
        float v = l[e];
        if (v > v1) { v1 = v; i1 = e; }
    }
    float e2 = expf(v1 - v0);
    float w0 = 1.0f / (1.0f + e2);
    float w1 = e2 * w0;
    tokE[2 * t] = i0;
    tokE[2 * t + 1] = i1;
    tokW[2 * t] = w0;
    tokW[2 * t + 1] = w1;
    atomicAdd(&counts[i0], 1);
    atomicAdd(&counts[i1], 1);
}

__global__ void offsets_k(const int* __restrict__ counts, int* __restrict__ offsets,
                          int* __restrict__ cursor) {
    if (threadIdx.x == 0 && blockIdx.x == 0) {
        int a = 0;
        for (int e = 0; e < E_; ++e) {
            offsets[e] = a;
            cursor[e] = a;
            a += counts[e];
        }
    }
}

__global__ __launch_bounds__(256) void assign_k(const int* __restrict__ tokE,
                                                int* __restrict__ cursor,
                                                int* __restrict__ rowTok,
                                                int* __restrict__ tokRow) {
    int t = blockIdx.x * 256 + threadIdx.x;
    if (t >= T_) return;
    for (int s = 0; s < 2; ++s) {
        int e = tokE[2 * t + s];
        int r = atomicAdd(&cursor[e], 1);
        rowTok[r] = t;
        tokRow[2 * t + s] = r;
    }
}

// gather pair rows: Ag[p][r][:] = h[p][rowTok[r]][:]
__global__ __launch_bounds__(256) void gather2_k(const short* __restrict__ h,
                                                 const int* __restrict__ rowTok,
                                                 short* __restrict__ Ag, size_t hPl, size_t aPl) {
    int id = blockIdx.x * 256 + threadIdx.x;  // r*96 + c (uint4 units)
    if (id >= 2 * T_ * 96) return;
    int p = blockIdx.y;
    int r = id / 96, c = id % 96;
    const uint4* src = (const uint4*)(h + p * hPl) + (size_t)rowTok[r] * 96 + c;
    ((uint4*)(Ag + p * aPl))[(size_t)r * 96 + c] = *src;
}

__global__ __launch_bounds__(256) void combine_k(const float* __restrict__ y2,
                                                 const int* __restrict__ tokRow,
                                                 const float* __restrict__ tokW,
                                                 float* __restrict__ x, short* __restrict__ xb,
                                                 size_t xbPl) {
    int id = blockIdx.x * 256 + threadIdx.x;
    if (id >= T_ * D_) return;
    int t = id / D_;
    float v = x[id] + tokW[2 * t] * y2[(size_t)tokRow[2 * t] * D_ + id % D_] +
              tokW[2 * t + 1] * y2[(size_t)tokRow[2 * t + 1] * D_ + id % D_];
    x[id] = v;
    split_store(v, xb + id, xbPl);
}

__global__ void pad_outb_k(const float* __restrict__ outb, float* __restrict__ obp) {
    int i = blockIdx.x * 256 + threadIdx.x;
    if (i < NPADO) obp[i] = (i < NS2) ? outb[i] : 0.0f;
}

// basisT pair [n][j], stride KPAD; j>=NS2 -> 0
__global__ __launch_bounds__(256) void basisT2_k(short* __restrict__ bT, size_t planeOff) {
    int id = blockIdx.x * 256 + threadIdx.x;
    if (id >= WIN_ * KPAD) return;
    int n = id / KPAD, j = id % KPAD;
    float val = 0.0f;
    if (j < NS2) {
        float wn = 0.5f - 0.5f * cosf(6.283185307179586f * (float)n / 1024.0f);
        int kf = (j < FBINS) ? j : (j - FBINS);
        float scale = (kf == 0 || kf == 512) ? (1.0f / 1024.0f) : (2.0f / 1024.0f);
        int m = (kf * n) & 1023;
        float th = 6.283185307179586f * (float)m / 1024.0f;
        if (j < FBINS) val = scale * cosf(th);
        else val = (kf == 0 || kf == 512) ? 0.0f : (-scale * sinf(th));
        val *= wn;
    }
    split_store(val, bT + id, planeOff);
}

__global__ __launch_bounds__(256) void ola_k(const float* __restrict__ frames,
                                             float* __restrict__ out, int total) {
    int id = blockIdx.x * 256 + threadIdx.x;
    if (id >= total) return;
    int b = id / OUTP, pout = id % OUTP;
    int p = pout + PAD_;
    int t1 = p >> 8;
    if (t1 > S_ - 1) t1 = S_ - 1;
    int t0 = p - (WIN_ - 1) + (HOP_ - 1);
    t0 = (t0 > 0) ? (t0 >> 8) : 0;
    float acc = 0.0f, env = 0.0f;
    for (int t = t0; t <= t1; ++t) {
        int n = p - (t << 8);
        float wn = 0.5f - 0.5f * cosf(6.283185307179586f * (float)n / 1024.0f);
        acc += frames[(((size_t)(b * S_ + t)) << 10) + n];
        env += wn * wn;
    }
    out[id] = acc / env;
}

// ======================= launcher =======================
extern "C" void kernel_launch(void* const* d_in, const int* in_sizes, int n_in, void* d_out,
                              int out_size, void* d_ws, size_t ws_size, hipStream_t stream) {
    const float* z    = (const float*)d_in[0];
    const float* in_w = (const float*)d_in[1];
    const float* in_b = (const float*)d_in[2];
    const float* ln1g = (const float*)d_in[3];
    const float* ln1b = (const float*)d_in[4];
    const float* wq   = (const float*)d_in[5];
    const float* bq   = (const float*)d_in[6];
    const float* wk   = (const float*)d_in[7];
    const float* bk   = (const float*)d_in[8];
    const float* wv   = (const float*)d_in[9];
    const float* bv   = (const float*)d_in[10];
    const float* wo   = (const float*)d_in[11];
    const float* bo   = (const float*)d_in[12];
    const float* ln2g = (const float*)d_in[13];
    const float* ln2b = (const float*)d_in[14];
    const float* gw   = (const float*)d_in[15];
    const float* ew1  = (const float*)d_in[16];
    const float* eb1  = (const float*)d_in[17];
    const float* ew2  = (const float*)d_in[18];
    const float* eb2  = (const float*)d_in[19];
    const float* outw = (const float*)d_in[20];
    const float* outb = (const float*)d_in[21];

    float* ws = (float*)d_ws;
    int* wsi = (int*)d_ws;
    const size_t TD = (size_t)T_ * D_;
    const size_t o_x      = 0;
    const size_t o_logits = TD;
    const size_t o_counts = o_logits + (size_t)T_ * E_;
    const size_t o_cursor = o_counts + 16;
    const size_t o_offs   = o_cursor + 16;
    const size_t o_tokE   = o_offs + 16;
    const size_t o_rowTok = o_tokE + 2 * T_;
    const size_t o_tokRow = o_rowTok + 2 * T_;
    const size_t o_tokW   = o_tokRow + 2 * T_;
    const size_t o_obp    = o_tokW + 2 * T_;
    const size_t o_W      = ((o_obp + NPADO + 127) / 128) * 128;
    const size_t WSLOT    = (size_t)D_ * D_;
    const size_t o_q      = o_W + 4 * WSLOT;
    const size_t o_k      = o_q + TD;
    const size_t o_v      = o_k + TD;
    const size_t o_h      = o_v + TD;
    const size_t o_ctx    = o_h + TD;
    const size_t o_eT     = o_ctx + TD;
    const size_t o_Ag     = o_eT + 2 * (size_t)FF_ * D_;
    const size_t AgF      = (size_t)AGR * D_;
    const size_t total    = o_Ag + AgF;
    if (ws_size < total * sizeof(float)) return;
    // overlays (phase-disjoint)
    const size_t o_h1     = o_W;
    const size_t o_y2     = o_Ag;
    const size_t o_zT     = o_eT;
    const size_t o_s      = o_eT;
    const size_t o_basisT = o_s + (size_t)T_ * KPAD;
    const size_t o_frames = o_basisT + (size_t)WIN_ * KPAD;
    const size_t o_qp     = o_eT;            // attn pair buffers overlay MoE region
    const size_t o_kp     = o_eT + TD;
    const size_t o_vp     = o_eT + 2 * TD;
    // plane offsets (shorts)
    const size_t PL_TD   = TD;
    const size_t PL_W    = (size_t)D_ * D_;
    const size_t PL_INW  = (size_t)D_ * CIN;
    const size_t PL_OUTW = (size_t)NPADO * D_;
    const size_t PL_E    = (size_t)FF_ * D_;
    const size_t EST     = 2 * PL_E;
    const size_t PL_AG   = (size_t)AGR * D_;
    const size_t PL_H1   = (size_t)AGR * FF_;
    const size_t PL_ZT   = (size_t)T_ * CIN;
    const size_t PL_S    = (size_t)T_ * KPAD;
    const size_t PL_BAS  = (size_t)WIN_ * KPAD;
    const size_t WSLOTSH = 2 * PL_W;

    dim3 blk(256);
    short* Wsh  = (short*)(ws + o_W);
    short* hP   = (short*)(ws + o_h);
    short* ctxP = (short*)(ws + o_ctx);
    short* eTP  = (short*)(ws + o_eT);
    short* AgP  = (short*)(ws + o_Ag);
    short* h1P  = (short*)(ws + o_h1);
    short* qpP  = (short*)(ws + o_qp);
    short* kpP  = (short*)(ws + o_kp);
    short* vpP  = (short*)(ws + o_vp);

    // ---- in projection ----
    tz2_k<<<cdiv(T_ * CIN, 256), blk, 0, stream>>>(z, (short*)(ws + o_zT), PL_ZT);
    transp2_k<<<dim3(24, 16, 1), blk, 0, stream>>>(in_w, Wsh, CIN, D_, D_, 0, 0, PL_INW);
    mm2_k<0><<<dim3(6, 16), blk, 0, stream>>>((short*)(ws + o_zT), (short*)(ws + o_zT) + PL_ZT,
                                              Wsh, Wsh + PL_INW, in_b, ws + o_x, nullptr, 0,
                                              D_, CIN, CIN, CIN, D_);

    for (int i = 0; i < 2; ++i) {
        const size_t wOff = (size_t)i * D_ * D_;
        const size_t bOff = (size_t)i * D_;
        transp2_k<<<dim3(24, 24, 1), blk, 0, stream>>>(wq + wOff, Wsh, D_, D_, D_, 0, 0, PL_W);
        transp2_k<<<dim3(24, 24, 1), blk, 0, stream>>>(wk + wOff, Wsh + WSLOTSH, D_, D_, D_, 0, 0, PL_W);
        transp2_k<<<dim3(24, 24, 1), blk, 0, stream>>>(wv + wOff, Wsh + 2 * WSLOTSH, D_, D_, D_, 0, 0, PL_W);
        transp2_k<<<dim3(24, 24, 1), blk, 0, stream>>>(wo + wOff, Wsh + 3 * WSLOTSH, D_, D_, D_, 0, 0, PL_W);

        ln_k<<<T_, blk, 0, stream>>>(ws + o_x, ln1g + bOff, ln1b + bOff, hP, PL_TD);
        mm2_k<0><<<dim3(6, 16), blk, 0, stream>>>(hP, hP + PL_TD, Wsh, Wsh + PL_W, bq + bOff,
                                                  ws + o_q, nullptr, 0, D_, D_, D_, D_, D_);
        mm2_k<0><<<dim3(6, 16), blk, 0, stream>>>(hP, hP + PL_TD, Wsh + WSLOTSH,
                                                  Wsh + WSLOTSH + PL_W, bk + bOff, ws + o_k,
                                                  nullptr, 0, D_, D_, D_, D_, D_);
        mm2_k<0><<<dim3(6, 16), blk, 0, stream>>>(hP, hP + PL_TD, Wsh + 2 * WSLOTSH,
                                                  Wsh + 2 * WSLOTSH + PL_W, bv + bOff, ws + o_v,
                                                  nullptr, 0, D_, D_, D_, D_, D_);
        if (i == 0) {
            rope_k<<<cdiv(T_ * 384, 256), blk, 0, stream>>>(ws + o_q);
            rope_k<<<cdiv(T_ * 384, 256), blk, 0, stream>>>(ws + o_k);
        }
        // split q/k into pairs; transpose+split v per head
        split_k<<<cdiv(T_ * D_, 256), blk, 0, stream>>>(ws + o_q, qpP);
        split_k<<<cdiv(T_ * D_, 256), blk, 0, stream>>>(ws + o_k, kpP);
        vt2_k<<<dim3(32, 2, B_ * NH), blk, 0, stream>>>(ws + o_v, vpP);
        // flash attention
        fattn_k<<<dim3(16, B_ * NH), blk, 0, stream>>>(qpP, kpP, vpP, ctxP);
        mm2_k<1><<<dim3(6, 16), blk, 0, stream>>>(ctxP, ctxP + PL_TD, Wsh + 3 * WSLOTSH,
                                                  Wsh + 3 * WSLOTSH + PL_W, bo + bOff, ws + o_x,
                                                  nullptr, 0, D_, D_, D_, D_, D_);
        // LN2 pair for FFN input + fused fp32 LN+gate for routing
        ln_k<<<T_, blk, 0, stream>>>(ws + o_x, ln2g + bOff, ln2b + bOff, hP, PL_TD);
        lngate_k<<<T_, blk, 0, stream>>>(ws + o_x, ln2g + bOff, ln2b + bOff,
                                         gw + (size_t)i * D_ * E_, ws + o_logits);
        zero_meta_k<<<1, 64, 0, stream>>>(wsi + o_counts);
        top2_k<<<cdiv(T_, 256), blk, 0, stream>>>(ws + o_logits, wsi + o_counts, wsi + o_tokE,
                                                  ws + o_tokW);
        offsets_k<<<1, 64, 0, stream>>>(wsi + o_counts, wsi + o_offs, wsi + o_cursor);
        assign_k<<<cdiv(T_, 256), blk, 0, stream>>>(wsi + o_tokE, wsi + o_cursor, wsi + o_rowTok,
                                                    wsi + o_tokRow);
        gather2_k<<<dim3(cdiv(2 * T_ * 96, 256), 2), blk, 0, stream>>>(hP, wsi + o_rowTok, AgP,
                                                                       PL_TD, PL_AG);
        // expert FFN in 4 groups of 2 experts
        for (int g = 0; g < 4; ++g) {
            transp2_k<<<dim3(64, 24, 2), blk, 0, stream>>>(
                ew1 + ((size_t)i * E_ + 2 * g) * D_ * FF_, eTP, D_, FF_, FF_,
                (size_t)D_ * FF_, EST, PL_E);
            mm2_moe_k<3><<<dim3(16, 33, 2), blk, 0, stream>>>(
                AgP, AgP + PL_AG, eTP, EST, PL_E, eb1 + (size_t)i * E_ * FF_ + 2 * g * FF_, FF_,
                nullptr, h1P, PL_H1, wsi + o_counts + 2 * g, wsi + o_offs + 2 * g,
                FF_, D_, D_, D_, FF_);
        }
        for (int g = 0; g < 4; ++g) {
            transp2_k<<<dim3(24, 64, 2), blk, 0, stream>>>(
                ew2 + ((size_t)i * E_ + 2 * g) * FF_ * D_, eTP, FF_, D_, D_,
                (size_t)FF_ * D_, EST, PL_E);
            mm2_moe_k<0><<<dim3(6, 33, 2), blk, 0, stream>>>(
                h1P, h1P + PL_H1, eTP, EST, PL_E, eb2 + (size_t)i * E_ * D_ + 2 * g * D_, D_,
                ws + o_y2, nullptr, 0, wsi + o_counts + 2 * g, wsi + o_offs + 2 * g,
                D_, FF_, FF_, FF_, D_);
        }
        combine_k<<<cdiv(T_ * D_, 256), blk, 0, stream>>>(ws + o_y2, wsi + o_tokRow, ws + o_tokW,
                                                          ws + o_x, ctxP, PL_TD);
    }

    // ---- output projection -> s pair ----
    transp2_k<<<dim3(36, 24, 1), blk, 0, stream>>>(outw, Wsh, D_, NS2, NPADO, 0, 0, PL_OUTW);
    pad_outb_k<<<cdiv(NPADO, 256), blk, 0, stream>>>(outb, ws + o_obp);
    mm2_k<2><<<dim3(NPADO / 128, 16), blk, 0, stream>>>(ctxP, ctxP + PL_TD, Wsh, Wsh + PL_OUTW,
                                                        ws + o_obp, nullptr, (short*)(ws + o_s),
                                                        PL_S, KPAD, D_, D_, D_, KPAD);
    // ---- ISTFT ----
    basisT2_k<<<cdiv(WIN_ * KPAD, 256), blk, 0, stream>>>((short*)(ws + o_basisT), PL_BAS);
    mm2_k<0><<<dim3(8, 16), blk, 0, stream>>>((short*)(ws + o_s), (short*)(ws + o_s) + PL_S,
                                              (short*)(ws + o_basisT),
                                              (short*)(ws + o_basisT) + PL_BAS, nullptr,
                                              ws + o_frames, nullptr, 0, WIN_, KPAD, KPAD, KPAD,
                                              WIN_);
    ola_k<<<cdiv(out_size, 256), blk, 0, stream>>>(ws + o_frames, (float*)d_out, out_size);
}

// Round 2
// 2133.611 us; speedup vs baseline: 1.2939x; 1.2939x over previous
//
#include <hip/hip_runtime.h>
#include <hip/hip_bf16.h>
#include <math.h>

#define B_    2
#define CIN   512
#define S_    1024
#define D_    768
#define NH    12
#define HD_   64
#define E_    8
#define FF_   2048
#define T_    2048
#define FBINS 513
#define NS2   1026
#define KPAD  1056              // NS2 padded to mult of 32
#define NPADO 1152              // NS2 padded to mult of 128
#define WIN_  1024
#define HOP_  256
#define PAD_  384
#define OUTP  262144
#define AGR   4224              // 2T + 128 pad rows

static inline int cdiv(int a, int b) { return (a + b - 1) / b; }

typedef _Float16 half8 __attribute__((ext_vector_type(8)));
typedef __attribute__((ext_vector_type(4))) float floatx4;

#define MFMA16(a, b, c) __builtin_amdgcn_mfma_f32_16x16x32_f16(a, b, c, 0, 0, 0)
#define LO_SCALE 2048.0f
#define LO_INV   (1.0f / 2048.0f)

// split fp32 -> (hi fp16, lo fp16 scaled by 2048); planes are short-typed
__device__ inline void split_store(float v, short* p, size_t planeOff) {
    _Float16 h = (_Float16)v;
    _Float16 l = (_Float16)((v - (float)h) * LO_SCALE);
    *(_Float16*)p = h;
    *(_Float16*)(p + planeOff) = l;
}

__device__ inline float gelu_f(float x) {
    float x3 = x * x * x;
    return 0.5f * x * (1.0f + tanhf(0.7978845608028654f * (x + 0.044715f * x3)));
}

__device__ inline void gl_lds16(const short* g, short* l) {
    __builtin_amdgcn_global_load_lds((const __attribute__((address_space(1))) void*)g,
                                     (__attribute__((address_space(3))) void*)l, 16, 0, 0);
}

// ===== split-fp16 MFMA GEMM core (128x128 tile, BK=32, 3 MFMAs per frag pair) =====
// Double-buffered: prefetch tile kt+1 before computing kt; ONE barrier per iter.
// MODE 0: f32 store; 1: f32 +=; 2: split-pair store; 3: gelu -> split-pair store
template <int MODE>
__global__ __launch_bounds__(256) void mm2_k(
    const short* __restrict__ Ah, const short* __restrict__ Al,
    const short* __restrict__ Bh, const short* __restrict__ Bl,
    const float* __restrict__ bias, float* __restrict__ Cf,
    short* __restrict__ Cp, size_t CpPl,
    int Nstore, int K, int SA, int SB, int SC) {
    __shared__ short AsH[2][4096], AsL[2][4096], BsH[2][4096], BsL[2][4096];
    int tid = threadIdx.x;
    int wave = tid >> 6, lane = tid & 63;
    int m0 = blockIdx.y * 128, n0 = blockIdx.x * 128;
    int wm = (wave & 1) * 64, wn = (wave >> 1) * 64;
    floatx4 a1[4][4], a2[4][4];
#pragma unroll
    for (int i = 0; i < 4; ++i)
#pragma unroll
        for (int j = 0; j < 4; ++j) {
            a1[i][j] = (floatx4){0.f, 0.f, 0.f, 0.f};
            a2[i][j] = (floatx4){0.f, 0.f, 0.f, 0.f};
        }
    int lm = lane & 15, lk = (lane >> 4) * 8;
    int fl0 = wave * 64 + lane, fl1 = fl0 + 256;
    int r0 = fl0 >> 2, c0 = (fl0 & 3) * 8;
    int r1 = fl1 >> 2, c1 = (fl1 & 3) * 8;
    int dst0 = wave * 512, dst1 = (wave + 4) * 512;
    int kIters = K >> 5;

    auto stage = [&](int kt, int bb) {
        int k0 = kt << 5;
        size_t a0 = (size_t)(m0 + r0) * SA + k0 + c0;
        size_t a1o = (size_t)(m0 + r1) * SA + k0 + c1;
        size_t b0 = (size_t)(n0 + r0) * SB + k0 + c0;
        size_t b1 = (size_t)(n0 + r1) * SB + k0 + c1;
        gl_lds16(Ah + a0, &AsH[bb][dst0]);
        gl_lds16(Ah + a1o, &AsH[bb][dst1]);
        gl_lds16(Al + a0, &AsL[bb][dst0]);
        gl_lds16(Al + a1o, &AsL[bb][dst1]);
        gl_lds16(Bh + b0, &BsH[bb][dst0]);
        gl_lds16(Bh + b1, &BsH[bb][dst1]);
        gl_lds16(Bl + b0, &BsL[bb][dst0]);
        gl_lds16(Bl + b1, &BsL[bb][dst1]);
    };

    stage(0, 0);
    __syncthreads();
    int cur = 0;
    for (int kt = 0; kt < kIters; ++kt) {
        if (kt + 1 < kIters) stage(kt + 1, cur ^ 1);
        const short* aH = AsH[cur];
        const short* aL = AsL[cur];
        const short* bH = BsH[cur];
        const short* bL = BsL[cur];
        half8 ah[4], al[4], bh[4], bl[4];
#pragma unroll
        for (int i = 0; i < 4; ++i) {
            int off = (wm + i * 16 + lm) * 32 + lk;
            ah[i] = *(const half8*)(aH + off);
            al[i] = *(const half8*)(aL + off);
        }
#pragma unroll
        for (int j = 0; j < 4; ++j) {
            int off = (wn + j * 16 + lm) * 32 + lk;
            bh[j] = *(const half8*)(bH + off);
            bl[j] = *(const half8*)(bL + off);
        }
#pragma unroll
        for (int i = 0; i < 4; ++i)
#pragma unroll
            for (int j = 0; j < 4; ++j) {
                a1[i][j] = MFMA16(ah[i], bh[j], a1[i][j]);
                a2[i][j] = MFMA16(ah[i], bl[j], a2[i][j]);
                a2[i][j] = MFMA16(al[i], bh[j], a2[i][j]);
            }
        __syncthreads();
        cur ^= 1;
    }
    int row4 = (lane >> 4) * 4;
#pragma unroll
    for (int i = 0; i < 4; ++i) {
        int row = m0 + wm + i * 16 + row4;
#pragma unroll
        for (int j = 0; j < 4; ++j) {
            int col = n0 + wn + j * 16 + lm;
            if (col < Nstore) {
                float bv = bias ? bias[col] : 0.0f;
#pragma unroll
                for (int r = 0; r < 4; ++r) {
                    float v = a1[i][j][r] + a2[i][j][r] * LO_INV + bv;
                    size_t idx = (size_t)(row + r) * SC + col;
                    if (MODE == 0) Cf[idx] = v;
                    else if (MODE == 1) Cf[idx] += v;
                    else if (MODE == 2) split_store(v, Cp + idx, CpPl);
                    else split_store(gelu_f(v), Cp + idx, CpPl);
                }
            }
        }
    }
}

// ===== grouped MoE variant over expert row-segments (2 experts per launch) =====
template <int MODE>
__global__ __launch_bounds__(256) void mm2_moe_k(
    const short* __restrict__ Agh, const short* __restrict__ Agl,
    const short* __restrict__ BT, size_t eStride, size_t bPl,
    const float* __restrict__ biasAll, int biasStride,
    float* __restrict__ Cf, short* __restrict__ Cp, size_t CpPl,
    const int* __restrict__ counts, const int* __restrict__ offsets,
    int N, int K, int SA, int SB, int SC) {
    int el = blockIdx.z;
    int nrows = counts[el];
    int m0 = blockIdx.y * 128;
    if (m0 >= nrows) return;
    int base = offsets[el];
    const short* Ah = Agh + (size_t)base * SA;
    const short* Al = Agl + (size_t)base * SA;
    const short* Bh = BT + (size_t)el * eStride;
    const short* Bl = Bh + bPl;
    const float* bias = biasAll + (size_t)el * biasStride;
    __shared__ short AsH[2][4096], AsL[2][4096], BsH[2][4096], BsL[2][4096];
    int tid = threadIdx.x;
    int wave = tid >> 6, lane = tid & 63;
    int n0 = blockIdx.x * 128;
    int wm = (wave & 1) * 64, wn = (wave >> 1) * 64;
    floatx4 a1[4][4], a2[4][4];
#pragma unroll
    for (int i = 0; i < 4; ++i)
#pragma unroll
        for (int j = 0; j < 4; ++j) {
            a1[i][j] = (floatx4){0.f, 0.f, 0.f, 0.f};
            a2[i][j] = (floatx4){0.f, 0.f, 0.f, 0.f};
        }
    int lm = lane & 15, lk = (lane >> 4) * 8;
    int fl0 = wave * 64 + lane, fl1 = fl0 + 256;
    int r0 = fl0 >> 2, c0 = (fl0 & 3) * 8;
    int r1 = fl1 >> 2, c1 = (fl1 & 3) * 8;
    int dst0 = wave * 512, dst1 = (wave + 4) * 512;
    int kIters = K >> 5;

    auto stage = [&](int kt, int bb) {
        int k0 = kt << 5;
        size_t a0 = (size_t)(m0 + r0) * SA + k0 + c0;
        size_t a1o = (size_t)(m0 + r1) * SA + k0 + c1;
        size_t b0 = (size_t)(n0 + r0) * SB + k0 + c0;
        size_t b1 = (size_t)(n0 + r1) * SB + k0 + c1;
        gl_lds16(Ah + a0, &AsH[bb][dst0]);
        gl_lds16(Ah + a1o, &AsH[bb][dst1]);
        gl_lds16(Al + a0, &AsL[bb][dst0]);
        gl_lds16(Al + a1o, &AsL[bb][dst1]);
        gl_lds16(Bh + b0, &BsH[bb][dst0]);
        gl_lds16(Bh + b1, &BsH[bb][dst1]);
        gl_lds16(Bl + b0, &BsL[bb][dst0]);
        gl_lds16(Bl + b1, &BsL[bb][dst1]);
    };

    stage(0, 0);
    __syncthreads();
    int cur = 0;
    for (int kt = 0; kt < kIters; ++kt) {
        if (kt + 1 < kIters) stage(kt + 1, cur ^ 1);
        const short* aH = AsH[cur];
        const short* aL = AsL[cur];
        const short* bH = BsH[cur];
        const short* bL = BsL[cur];
        half8 ah[4], al[4], bh[4], bl[4];
#pragma unroll
        for (int i = 0; i < 4; ++i) {
            int off = (wm + i * 16 + lm) * 32 + lk;
            ah[i] = *(const half8*)(aH + off);
            al[i] = *(const half8*)(aL + off);
        }
#pragma unroll
        for (int j = 0; j < 4; ++j) {
            int off = (wn + j * 16 + lm) * 32 + lk;
            bh[j] = *(const half8*)(bH + off);
            bl[j] = *(const half8*)(bL + off);
        }
#pragma unroll
        for (int i = 0; i < 4; ++i)
#pragma unroll
            for (int j = 0; j < 4; ++j) {
                a1[i][j] = MFMA16(ah[i], bh[j], a1[i][j]);
                a2[i][j] = MFMA16(ah[i], bl[j], a2[i][j]);
                a2[i][j] = MFMA16(al[i], bh[j], a2[i][j]);
            }
        __syncthreads();
        cur ^= 1;
    }
    int row4 = (lane >> 4) * 4;
#pragma unroll
    for (int i = 0; i < 4; ++i) {
        int rl = m0 + wm + i * 16 + row4;
#pragma unroll
        for (int j = 0; j < 4; ++j) {
            int col = n0 + wn + j * 16 + lm;
            if (col < N) {
                float bv = bias[col];
#pragma unroll
                for (int r = 0; r < 4; ++r) {
                    if (rl + r < nrows) {
                        float v = a1[i][j][r] + a2[i][j][r] * LO_INV + bv;
                        size_t idx = (size_t)(base + rl + r) * SC + col;
                        if (MODE == 0) Cf[idx] = v;
                        else split_store(gelu_f(v), Cp + idx, CpPl);
                    }
                }
            }
        }
    }
}

// ===== transpose fp32 [Z][R][C] -> split-pair [Z][Cout][R] (zero rows c>=C) =====
__global__ __launch_bounds__(256) void transp2_k(const float* __restrict__ src,
                                                 short* __restrict__ dst, int R, int C, int Cout,
                                                 size_t srcZ, size_t dstZ, size_t planeOff) {
    __shared__ float tile[32][33];
    int z = blockIdx.z;
    src += (size_t)z * srcZ;
    dst += (size_t)z * dstZ;
    int c0 = blockIdx.x * 32, r0 = blockIdx.y * 32;
    int tx = threadIdx.x & 31, ty = threadIdx.x >> 5;
    for (int i = ty; i < 32; i += 8) {
        int r = r0 + i, c = c0 + tx;
        tile[i][tx] = (r < R && c < C) ? src[(size_t)r * C + c] : 0.0f;
    }
    __syncthreads();
    for (int i = ty; i < 32; i += 8) {
        int cc = c0 + i, rr = r0 + tx;
        if (cc < Cout && rr < R) split_store(tile[tx][i], dst + (size_t)cc * R + rr, planeOff);
    }
}

// ===== transpose z: [B,CIN,S] -> zT pair [t][c] =====
__global__ __launch_bounds__(256) void tz2_k(const float* __restrict__ z, short* __restrict__ xT,
                                             size_t planeOff) {
    int id = blockIdx.x * 256 + threadIdx.x;
    if (id >= T_ * CIN) return;
    int t = id >> 9, c = id & 511;
    int b = t >> 10, l = t & 1023;
    split_store(z[((size_t)b * CIN + c) * S_ + l], xT + id, planeOff);
}

// ===== LayerNorm per token -> split pair =====
__global__ __launch_bounds__(256) void ln_k(const float* __restrict__ x,
                                            const float* __restrict__ g,
                                            const float* __restrict__ b, short* __restrict__ h,
                                            size_t planeOff) {
    int t = blockIdx.x;
    int tid = threadIdx.x;
    __shared__ float row[D_];
    __shared__ float red[256];
    const float* xr = x + (size_t)t * D_;
    float s = 0.0f;
    for (int i = tid; i < D_; i += 256) {
        float v = xr[i];
        row[i] = v;
        s += v;
    }
    red[tid] = s;
    __syncthreads();
    for (int st = 128; st > 0; st >>= 1) {
        if (tid < st) red[tid] += red[tid + st];
        __syncthreads();
    }
    float mean = red[0] / (float)D_;
    __syncthreads();
    float s2 = 0.0f;
    for (int i = tid; i < D_; i += 256) {
        float d = row[i] - mean;
        s2 += d * d;
    }
    red[tid] = s2;
    __syncthreads();
    for (int st = 128; st > 0; st >>= 1) {
        if (tid < st) red[tid] += red[tid + st];
        __syncthreads();
    }
    float rstd = rsqrtf(red[0] / (float)D_ + 1e-5f);
    for (int i = tid; i < D_; i += 256)
        split_store((row[i] - mean) * rstd * g[i] + b[i], h + (size_t)t * D_ + i, planeOff);
}

// ===== fused fp32 LN + gating logits =====
__global__ __launch_bounds__(256) void lngate_k(const float* __restrict__ x,
                                                const float* __restrict__ g,
                                                const float* __restrict__ b,
                                                const float* __restrict__ gw,
                                                float* __restrict__ logits) {
    int t = blockIdx.x;
    int tid = threadIdx.x;
    __shared__ float row[D_];
    __shared__ float red[256];
    const float* xr = x + (size_t)t * D_;
    float s = 0.0f;
    for (int i = tid; i < D_; i += 256) {
        float v = xr[i];
        row[i] = v;
        s += v;
    }
    red[tid] = s;
    __syncthreads();
    for (int st = 128; st > 0; st >>= 1) {
        if (tid < st) red[tid] += red[tid + st];
        __syncthreads();
    }
    float mean = red[0] / (float)D_;
    __syncthreads();
    float s2 = 0.0f;
    for (int i = tid; i < D_; i += 256) {
        float d = row[i] - mean;
        s2 += d * d;
    }
    red[tid] = s2;
    __syncthreads();
    for (int st = 128; st > 0; st >>= 1) {
        if (tid < st) red[tid] += red[tid + st];
        __syncthreads();
    }
    float rstd = rsqrtf(red[0] / (float)D_ + 1e-5f);
    __syncthreads();
    int e = tid >> 5, lane = tid & 31;
    float acc = 0.0f;
    for (int d = lane; d < D_; d += 32)
        acc += ((row[d] - mean) * rstd * g[d] + b[d]) * gw[d * E_ + e];
    red[tid] = acc;
    __syncthreads();
    for (int st = 16; st > 0; st >>= 1) {
        if (lane < st) red[tid] += red[tid + st];
        __syncthreads();
    }
    if (lane == 0) logits[t * E_ + e] = red[tid];
}

// ===== concat 3 bias vectors [768] -> [2304] =====
__global__ void catb_k(const float* __restrict__ a, const float* __restrict__ b,
                       const float* __restrict__ c, float* __restrict__ dst) {
    int i = blockIdx.x * 256 + threadIdx.x;
    if (i < 768) dst[i] = a[i];
    else if (i < 1536) dst[i] = b[i - 768];
    else if (i < 2304) dst[i] = c[i - 1536];
}

// ===== RoPE on fused qkv [T][2304] (cols 0..767=q, 768..1535=k) -> split pairs =====
__global__ __launch_bounds__(256) void ropesplit_k(const float* __restrict__ qkv,
                                                   short* __restrict__ qd,
                                                   short* __restrict__ kd) {
    int id = blockIdx.x * 256 + threadIdx.x;
    if (id >= T_ * 384) return;
    int t = id / 384, j = id % 384;
    int pos = t & 1023;
    float inv = expf(-(float)j * (9.210340371976184f / 384.0f));
    float ang = (float)pos * inv;
    float sn, cs;
    sincosf(ang, &sn, &cs);
    const float* pq = qkv + (size_t)t * 2304 + 2 * j;
    const float* pk = pq + 768;
    const size_t PL = (size_t)T_ * D_;
    size_t o = (size_t)t * D_ + 2 * j;
    float q1 = pq[0], q2 = pq[1];
    split_store(q1 * cs - q2 * sn, qd + o, PL);
    split_store(q1 * sn + q2 * cs, qd + o + 1, PL);
    float k1 = pk[0], k2 = pk[1];
    split_store(k1 * cs - k2 * sn, kd + o, PL);
    split_store(k1 * sn + k2 * cs, kd + o + 1, PL);
}

// ===== q,k columns of fused qkv -> split pairs (no rope) =====
__global__ __launch_bounds__(256) void qksplit_k(const float* __restrict__ qkv,
                                                 short* __restrict__ qd,
                                                 short* __restrict__ kd) {
    int id = blockIdx.x * 256 + threadIdx.x;
    if (id >= T_ * D_) return;
    int t = id / D_, c = id % D_;
    const size_t PL = (size_t)T_ * D_;
    split_store(qkv[(size_t)t * 2304 + c], qd + id, PL);
    split_store(qkv[(size_t)t * 2304 + 768 + c], kd + id, PL);
}

// ===== V cols of fused qkv [T][2304] -> V^T pair [BH][64][S] =====
__global__ __launch_bounds__(256) void vt2_k(const float* __restrict__ qkv,
                                             short* __restrict__ vp) {
    __shared__ float tile[32][33];
    int bh = blockIdx.z, b = bh / NH, h = bh % NH;
    int j0 = blockIdx.x * 32, d0 = blockIdx.y * 32;
    int tx = threadIdx.x & 31, ty = threadIdx.x >> 5;
    for (int i = ty; i < 32; i += 8)
        tile[i][tx] = qkv[(size_t)(b * S_ + j0 + i) * 2304 + 1536 + h * 64 + d0 + tx];
    __syncthreads();
    for (int i = ty; i < 32; i += 8)
        split_store(tile[tx][i], vp + ((size_t)bh * 64 + d0 + i) * S_ + j0 + tx,
                    (size_t)T_ * D_);
}

// ===== flash attention: split-fp16 MFMA, online softmax, causal =====
// grid (8 balanced q-tile pairs, 24 bh), block 256 (4 waves x 16 Q-rows).
// Each block handles q-tiles {qp, 15-qp}: 9 kv-iterations each -> perfect balance.
// LDS tiles use a slot^(row&7) XOR swizzle (16B granularity) to reach the 8-round
// b128 minimum: staging pre-swizzles the GLOBAL source column (gl_lds dest linear).
__global__ __launch_bounds__(256) void fattn_k(const short* __restrict__ qp,
                                               const short* __restrict__ kp,
                                               const short* __restrict__ vp,
                                               short* __restrict__ ctx) {
    __shared__ short sQ[2][64 * 64];
    __shared__ short sK[2][128 * 64];
    __shared__ short sV[2][64 * 128];
    __shared__ short sP[2][4][16 * 128];
    const size_t PL = (size_t)T_ * D_;
    int qpair = blockIdx.x, bh = blockIdx.y;
    int b = bh / NH, h = bh % NH;
    int tid = threadIdx.x, wave = tid >> 6, lane = tid & 63;
    int quad = lane >> 4, lm = lane & 15;
    int lr8 = lane >> 3;                         // row-in-8-chunk for 64-short rows
    int lc8 = ((lane & 7) ^ lr8) * 8;            // pre-swizzled source col (64-short rows)
    int lm7 = lm & 7;                            // read-side row&7 (rows = base + lm)

    for (int hh = 0; hh < 2; ++hh) {
        int qt = hh ? (15 - qpair) : qpair;
        int t0 = b * S_ + qt * 64;
        {   // stage Q: per wave, 2 chunks of 8 rows per plane (swizzled source)
#pragma unroll
            for (int pl = 0; pl < 2; ++pl)
#pragma unroll
                for (int c = 0; c < 2; ++c) {
                    int r8 = wave * 16 + c * 8;
                    gl_lds16(qp + pl * PL + (size_t)(t0 + r8 + lr8) * D_ + h * 64 + lc8,
                             &sQ[pl][r8 * 64]);
                }
        }
        floatx4 o1[4], o2[4];
#pragma unroll
        for (int n = 0; n < 4; ++n) {
            o1[n] = (floatx4){0.f, 0.f, 0.f, 0.f};
            o2[n] = (floatx4){0.f, 0.f, 0.f, 0.f};
        }
        float mrow[4] = {-1e30f, -1e30f, -1e30f, -1e30f};
        float lrow[4] = {0.f, 0.f, 0.f, 0.f};
        int ktmax = qt >> 1;
        for (int kt = 0; kt <= ktmax; ++kt) {
            {   // stage K: per wave, 4 chunks of 8 rows per plane (swizzled source)
#pragma unroll
                for (int pl = 0; pl < 2; ++pl)
#pragma unroll
                    for (int c = 0; c < 4; ++c) {
                        int r8 = wave * 32 + c * 8;
                        gl_lds16(kp + pl * PL +
                                     (size_t)(b * S_ + kt * 128 + r8 + lr8) * D_ + h * 64 + lc8,
                                 &sK[pl][r8 * 64]);
                    }
                // stage V^T: per wave, 4 chunks of 4 rows (128-short rows, swizzled source)
                int vr = lane >> 4;
#pragma unroll
                for (int pl = 0; pl < 2; ++pl)
#pragma unroll
                    for (int c = 0; c < 4; ++c) {
                        int r4 = wave * 16 + c * 4;
                        int vcs = (((lane & 15) ^ (((c & 1) << 2) + vr))) * 8;
                        gl_lds16(vp + pl * PL + ((size_t)bh * 64 + r4 + vr) * S_ + kt * 128 + vcs,
                                 &sV[pl][r4 * 128]);
                    }
            }
            __syncthreads();
            // ---- S = Q K^T * scale (split-fp16) ----
            half8 qh[2], ql[2];
#pragma unroll
            for (int ks = 0; ks < 2; ++ks) {
                int off = (wave * 16 + lm) * 64 + ((ks * 4 + quad) ^ lm7) * 8;
                qh[ks] = *(const half8*)&sQ[0][off];
                ql[ks] = *(const half8*)&sQ[1][off];
            }
            floatx4 sacc[8];
#pragma unroll
            for (int nt = 0; nt < 8; ++nt) {
                floatx4 c1 = (floatx4){0.f, 0.f, 0.f, 0.f};
                floatx4 c2 = (floatx4){0.f, 0.f, 0.f, 0.f};
#pragma unroll
                for (int ks = 0; ks < 2; ++ks) {
                    int off = (nt * 16 + lm) * 64 + ((ks * 4 + quad) ^ lm7) * 8;
                    half8 kh = *(const half8*)&sK[0][off];
                    half8 kl = *(const half8*)&sK[1][off];
                    c1 = MFMA16(qh[ks], kh, c1);
                    c2 = MFMA16(qh[ks], kl, c2);
                    c2 = MFMA16(ql[ks], kh, c2);
                }
#pragma unroll
                for (int r = 0; r < 4; ++r) sacc[nt][r] = (c1[r] + c2[r] * LO_INV) * 0.125f;
            }
            if (kt == ktmax) {  // causal mask on the diagonal tile
#pragma unroll
                for (int nt = 0; nt < 8; ++nt) {
                    int col = kt * 128 + nt * 16 + lm;
#pragma unroll
                    for (int r = 0; r < 4; ++r) {
                        int rowg = qt * 64 + wave * 16 + quad * 4 + r;
                        if (col > rowg) sacc[nt][r] = -1e30f;
                    }
                }
            }
            // ---- online softmax (wave-local; rows live in 16-lane quads) ----
            float mnew[4], al[4], ls[4];
#pragma unroll
            for (int r = 0; r < 4; ++r) {
                float mx = sacc[0][r];
#pragma unroll
                for (int nt = 1; nt < 8; ++nt) mx = fmaxf(mx, sacc[nt][r]);
#pragma unroll
                for (int msk = 1; msk < 16; msk <<= 1) mx = fmaxf(mx, __shfl_xor(mx, msk));
                mnew[r] = fmaxf(mrow[r], mx);
                al[r] = __expf(mrow[r] - mnew[r]);
                mrow[r] = mnew[r];
                ls[r] = 0.f;
            }
#pragma unroll
            for (int nt = 0; nt < 8; ++nt)
#pragma unroll
                for (int r = 0; r < 4; ++r) {
                    float p = __expf(sacc[nt][r] - mnew[r]);
                    ls[r] += p;
                    _Float16 ph = (_Float16)p;
                    _Float16 plo = (_Float16)((p - (float)ph) * LO_SCALE);
                    int rowp = quad * 4 + r;
                    int off = rowp * 128 + ((nt * 2 + (lm >> 3)) ^ (rowp & 7)) * 8 + (lm & 7);
                    *(_Float16*)&sP[0][wave][off] = ph;
                    *(_Float16*)&sP[1][wave][off] = plo;
                }
#pragma unroll
            for (int r = 0; r < 4; ++r) {
#pragma unroll
                for (int msk = 1; msk < 16; msk <<= 1) ls[r] += __shfl_xor(ls[r], msk);
                lrow[r] = lrow[r] * al[r] + ls[r];
            }
#pragma unroll
            for (int n = 0; n < 4; ++n)
#pragma unroll
                for (int r = 0; r < 4; ++r) {
                    o1[n][r] *= al[r];
                    o2[n][r] *= al[r];
                }
            // ---- O += P V (split-fp16; P via per-wave LDS roundtrip) ----
            half8 ph8[4], pl8[4];
#pragma unroll
            for (int ks = 0; ks < 4; ++ks) {
                int off = lm * 128 + ((ks * 4 + quad) ^ lm7) * 8;
                ph8[ks] = *(const half8*)&sP[0][wave][off];
                pl8[ks] = *(const half8*)&sP[1][wave][off];
            }
#pragma unroll
            for (int nt2 = 0; nt2 < 4; ++nt2) {
#pragma unroll
                for (int ks = 0; ks < 4; ++ks) {
                    int off = (nt2 * 16 + lm) * 128 + ((ks * 4 + quad) ^ lm7) * 8;
                    half8 vh = *(const half8*)&sV[0][off];
                    half8 vl = *(const half8*)&sV[1][off];
                    o1[nt2] = MFMA16(ph8[ks], vh, o1[nt2]);
                    o2[nt2] = MFMA16(ph8[ks], vl, o2[nt2]);
                    o2[nt2] = MFMA16(pl8[ks], vh, o2[nt2]);
                }
            }
            __syncthreads();
        }
        // ---- epilogue: normalize, split-store ctx ----
#pragma unroll
        for (int r = 0; r < 4; ++r) {
            float inv = 1.0f / lrow[r];
            int rowg = t0 + wave * 16 + quad * 4 + r;
#pragma unroll
            for (int nt2 = 0; nt2 < 4; ++nt2) {
                float val = (o1[nt2][r] + o2[nt2][r] * LO_INV) * inv;
                int col = h * 64 + nt2 * 16 + lm;
                split_store(val, ctx + (size_t)rowg * D_ + col, PL);
            }
        }
    }
}

__global__ void zero_meta_k(int* __restrict__ counts) {
    int i = threadIdx.x;
    if (i < E_) counts[i] = 0;
}

__global__ __launch_bounds__(256) void top2_k(const float* __restrict__ logits,
                                              int* __restrict__ counts, int* __restrict__ tokE,
                                              float* __restrict__ tokW) {
    int t = blockIdx.x * 256 + threadIdx.x;
    if (t >= T_) return;
    const float* l = logits + t * E_;
    int i0 = 0;
    float v0 = l[0];
    for (int e = 1; e < E_; ++e) {
        float v = l[e];
        if (v > v0) { v0 = v; i0 = e; }
    }
    int i1 = -1;
    float v1 = -1e30f;
    for (int e = 0; e < E_; ++e) {
        if (e == i0) continue;
        float v = l[e];
        if (v > v1) { v1 = v; i1 = e; }
    }
    float e2 = expf(v1 - v0);
    float w0 = 1.0f / (1.0f + e2);
    float w1 = e2 * w0;
    tokE[2 * t] = i0;
    tokE[2 * t + 1] = i1;
    tokW[2 * t] = w0;
    tokW[2 * t + 1] = w1;
    atomicAdd(&counts[i0], 1);
    atomicAdd(&counts[i1], 1);
}

__global__ void offsets_k(const int* __restrict__ counts, int* __restrict__ offsets,
                          int* __restrict__ cursor) {
    if (threadIdx.x == 0 && blockIdx.x == 0) {
        int a = 0;
        for (int e = 0; e < E_; ++e) {
            offsets[e] = a;
            cursor[e] = a;
            a += counts[e];
        }
    }
}

__global__ __launch_bounds__(256) void assign_k(const int* __restrict__ tokE,
                                                int* __restrict__ cursor,
                                                int* __restrict__ rowTok,
                                                int* __restrict__ tokRow) {
    int t = blockIdx.x * 256 + threadIdx.x;
    if (t >= T_) return;
    for (int s = 0; s < 2; ++s) {
        int e = tokE[2 * t + s];
        int r = atomicAdd(&cursor[e], 1);
        rowTok[r] = t;
        tokRow[2 * t + s] = r;
    }
}

// gather pair rows: Ag[p][r][:] = h[p][rowTok[r]][:]
__global__ __launch_bounds__(256) void gather2_k(const short* __restrict__ h,
                                                 const int* __restrict__ rowTok,
                                                 short* __restrict__ Ag, size_t hPl, size_t aPl) {
    int id = blockIdx.x * 256 + threadIdx.x;  // r*96 + c (uint4 units)
    if (id >= 2 * T_ * 96) return;
    int p = blockIdx.y;
    int r = id / 96, c = id % 96;
    const uint4* src = (const uint4*)(h + p * hPl) + (size_t)rowTok[r] * 96 + c;
    ((uint4*)(Ag + p * aPl))[(size_t)r * 96 + c] = *src;
}

__global__ __launch_bounds__(256) void combine_k(const float* __restrict__ y2,
                                                 const int* __restrict__ tokRow,
                                                 const float* __restrict__ tokW,
                                                 float* __restrict__ x, short* __restrict__ xb,
                                                 size_t xbPl) {
    int id = blockIdx.x * 256 + threadIdx.x;
    if (id >= T_ * D_) return;
    int t = id / D_;
    float v = x[id] + tokW[2 * t] * y2[(size_t)tokRow[2 * t] * D_ + id % D_] +
              tokW[2 * t + 1] * y2[(size_t)tokRow[2 * t + 1] * D_ + id % D_];
    x[id] = v;
    split_store(v, xb + id, xbPl);
}

__global__ void pad_outb_k(const float* __restrict__ outb, float* __restrict__ obp) {
    int i = blockIdx.x * 256 + threadIdx.x;
    if (i < NPADO) obp[i] = (i < NS2) ? outb[i] : 0.0f;
}

// basisT pair [n][j], stride KPAD; j>=NS2 -> 0
__global__ __launch_bounds__(256) void basisT2_k(short* __restrict__ bT, size_t planeOff) {
    int id = blockIdx.x * 256 + threadIdx.x;
    if (id >= WIN_ * KPAD) return;
    int n = id / KPAD, j = id % KPAD;
    float val = 0.0f;
    if (j < NS2) {
        float wn = 0.5f - 0.5f * cosf(6.283185307179586f * (float)n / 1024.0f);
        int kf = (j < FBINS) ? j : (j - FBINS);
        float scale = (kf == 0 || kf == 512) ? (1.0f / 1024.0f) : (2.0f / 1024.0f);
        int m = (kf * n) & 1023;
        float th = 6.283185307179586f * (float)m / 1024.0f;
        if (j < FBINS) val = scale * cosf(th);
        else val = (kf == 0 || kf == 512) ? 0.0f : (-scale * sinf(th));
        val *= wn;
    }
    split_store(val, bT + id, planeOff);
}

__global__ __launch_bounds__(256) void ola_k(const float* __restrict__ frames,
                                             float* __restrict__ out, int total) {
    int id = blockIdx.x * 256 + threadIdx.x;
    if (id >= total) return;
    int b = id / OUTP, pout = id % OUTP;
    int p = pout + PAD_;
    int t1 = p >> 8;
    if (t1 > S_ - 1) t1 = S_ - 1;
    int t0 = p - (WIN_ - 1) + (HOP_ - 1);
    t0 = (t0 > 0) ? (t0 >> 8) : 0;
    float acc = 0.0f, env = 0.0f;
    for (int t = t0; t <= t1; ++t) {
        int n = p - (t << 8);
        float wn = 0.5f - 0.5f * cosf(6.283185307179586f * (float)n / 1024.0f);
        acc += frames[(((size_t)(b * S_ + t)) << 10) + n];
        env += wn * wn;
    }
    out[id] = acc / env;
}

// ======================= launcher =======================
extern "C" void kernel_launch(void* const* d_in, const int* in_sizes, int n_in, void* d_out,
                              int out_size, void* d_ws, size_t ws_size, hipStream_t stream) {
    const float* z    = (const float*)d_in[0];
    const float* in_w = (const float*)d_in[1];
    const float* in_b = (const float*)d_in[2];
    const float* ln1g = (const float*)d_in[3];
    const float* ln1b = (const float*)d_in[4];
    const float* wq   = (const float*)d_in[5];
    const float* bq   = (const float*)d_in[6];
    const float* wk   = (const float*)d_in[7];
    const float* bk   = (const float*)d_in[8];
    const float* wv   = (const float*)d_in[9];
    const float* bv   = (const float*)d_in[10];
    const float* wo   = (const float*)d_in[11];
    const float* bo   = (const float*)d_in[12];
    const float* ln2g = (const float*)d_in[13];
    const float* ln2b = (const float*)d_in[14];
    const float* gw   = (const float*)d_in[15];
    const float* ew1  = (const float*)d_in[16];
    const float* eb1  = (const float*)d_in[17];
    const float* ew2  = (const float*)d_in[18];
    const float* eb2  = (const float*)d_in[19];
    const float* outw = (const float*)d_in[20];
    const float* outb = (const float*)d_in[21];

    float* ws = (float*)d_ws;
    int* wsi = (int*)d_ws;
    const size_t TD = (size_t)T_ * D_;
    const size_t o_x      = 0;
    const size_t o_logits = TD;
    const size_t o_counts = o_logits + (size_t)T_ * E_;
    const size_t o_cursor = o_counts + 16;
    const size_t o_offs   = o_cursor + 16;
    const size_t o_tokE   = o_offs + 16;
    const size_t o_rowTok = o_tokE + 2 * T_;
    const size_t o_tokRow = o_rowTok + 2 * T_;
    const size_t o_tokW   = o_tokRow + 2 * T_;
    const size_t o_obp    = o_tokW + 2 * T_;
    const size_t o_W      = ((o_obp + NPADO + 127) / 128) * 128;
    const size_t WSLOT    = (size_t)D_ * D_;
    const size_t o_q      = o_W + 4 * WSLOT;
    const size_t o_k      = o_q + TD;
    const size_t o_v      = o_k + TD;
    const size_t o_h      = o_v + TD;
    const size_t o_ctx    = o_h + TD;
    const size_t o_eT     = o_ctx + TD;
    const size_t o_Ag     = o_eT + 2 * (size_t)FF_ * D_;
    const size_t AgF      = (size_t)AGR * D_;
    const size_t total    = o_Ag + AgF;
    if (ws_size < total * sizeof(float)) return;
    // overlays (phase-disjoint)
    const size_t o_h1     = o_W;
    const size_t o_y2     = o_Ag;
    const size_t o_zT     = o_eT;
    const size_t o_s      = o_eT;
    const size_t o_basisT = o_s + (size_t)T_ * KPAD;
    const size_t o_frames = o_basisT + (size_t)WIN_ * KPAD;
    const size_t o_qp     = o_eT;            // attn pair buffers overlay MoE region
    const size_t o_kp     = o_eT + TD;
    const size_t o_vp     = o_eT + 2 * TD;
    // plane offsets (shorts)
    const size_t PL_TD   = TD;
    const size_t PL_W    = (size_t)D_ * D_;
    const size_t PL_INW  = (size_t)D_ * CIN;
    const size_t PL_OUTW = (size_t)NPADO * D_;
    const size_t PL_E    = (size_t)FF_ * D_;
    const size_t EST     = 2 * PL_E;
    const size_t PL_AG   = (size_t)AGR * D_;
    const size_t PL_H1   = (size_t)AGR * FF_;
    const size_t PL_ZT   = (size_t)T_ * CIN;
    const size_t PL_S    = (size_t)T_ * KPAD;
    const size_t PL_BAS  = (size_t)WIN_ * KPAD;

    dim3 blk(256);
    short* Wsh  = (short*)(ws + o_W);
    short* hP   = (short*)(ws + o_h);
    short* ctxP = (short*)(ws + o_ctx);
    short* eTP  = (short*)(ws + o_eT);
    short* AgP  = (short*)(ws + o_Ag);
    short* h1P  = (short*)(ws + o_h1);
    short* qpP  = (short*)(ws + o_qp);
    short* kpP  = (short*)(ws + o_kp);
    short* vpP  = (short*)(ws + o_vp);

    // ---- in projection ----
    tz2_k<<<cdiv(T_ * CIN, 256), blk, 0, stream>>>(z, (short*)(ws + o_zT), PL_ZT);
    transp2_k<<<dim3(24, 16, 1), blk, 0, stream>>>(in_w, Wsh, CIN, D_, D_, 0, 0, PL_INW);
    mm2_k<0><<<dim3(6, 16), blk, 0, stream>>>((short*)(ws + o_zT), (short*)(ws + o_zT) + PL_ZT,
                                              Wsh, Wsh + PL_INW, in_b, ws + o_x, nullptr, 0,
                                              D_, CIN, CIN, CIN, D_);

    for (int i = 0; i < 2; ++i) {
        const size_t wOff = (size_t)i * D_ * D_;
        const size_t bOff = (size_t)i * D_;
        // fused QKV B^T: hi planes [q|k|v] then lo planes [q|k|v]
        transp2_k<<<dim3(24, 24, 1), blk, 0, stream>>>(wq + wOff, Wsh, D_, D_, D_, 0, 0, 3 * PL_W);
        transp2_k<<<dim3(24, 24, 1), blk, 0, stream>>>(wk + wOff, Wsh + PL_W, D_, D_, D_, 0, 0, 3 * PL_W);
        transp2_k<<<dim3(24, 24, 1), blk, 0, stream>>>(wv + wOff, Wsh + 2 * PL_W, D_, D_, D_, 0, 0, 3 * PL_W);
        transp2_k<<<dim3(24, 24, 1), blk, 0, stream>>>(wo + wOff, Wsh + 6 * PL_W, D_, D_, D_, 0, 0, PL_W);
        catb_k<<<cdiv(2304, 256), blk, 0, stream>>>(bq + bOff, bk + bOff, bv + bOff,
                                                    ws + o_logits);

        ln_k<<<T_, blk, 0, stream>>>(ws + o_x, ln1g + bOff, ln1b + bOff, hP, PL_TD);
        // fused QKV GEMM: [T][768] x [2304][768]^T -> [T][2304] (q|k|v interleaved per row)
        mm2_k<0><<<dim3(18, 16), blk, 0, stream>>>(hP, hP + PL_TD, Wsh, Wsh + 3 * PL_W,
                                                   ws + o_logits, ws + o_q, nullptr, 0,
                                                   2304, D_, D_, D_, 2304);
        if (i == 0) {
            ropesplit_k<<<cdiv(T_ * 384, 256), blk, 0, stream>>>(ws + o_q, qpP, kpP);
        } else {
            qksplit_k<<<cdiv(T_ * D_, 256), blk, 0, stream>>>(ws + o_q, qpP, kpP);
        }
        vt2_k<<<dim3(32, 2, B_ * NH), blk, 0, stream>>>(ws + o_q, vpP);
        // flash attention (balanced q-tile pairs)
        fattn_k<<<dim3(8, B_ * NH), blk, 0, stream>>>(qpP, kpP, vpP, ctxP);
        mm2_k<1><<<dim3(6, 16), blk, 0, stream>>>(ctxP, ctxP + PL_TD, Wsh + 6 * PL_W,
                                                  Wsh + 7 * PL_W, bo + bOff, ws + o_x,
                                                  nullptr, 0, D_, D_, D_, D_, D_);
        // LN2 pair for FFN input + fused fp32 LN+gate for routing
        ln_k<<<T_, blk, 0, stream>>>(ws + o_x, ln2g + bOff, ln2b + bOff, hP, PL_TD);
        lngate_k<<<T_, blk, 0, stream>>>(ws + o_x, ln2g + bOff, ln2b + bOff,
                                         gw + (size_t)i * D_ * E_, ws + o_logits);
        zero_meta_k<<<1, 64, 0, stream>>>(wsi + o_counts);
        top2_k<<<cdiv(T_, 256), blk, 0, stream>>>(ws + o_logits, wsi + o_counts, wsi + o_tokE,
                                                  ws + o_tokW);
        offsets_k<<<1, 64, 0, stream>>>(wsi + o_counts, wsi + o_offs, wsi + o_cursor);
        assign_k<<<cdiv(T_, 256), blk, 0, stream>>>(wsi + o_tokE, wsi + o_cursor, wsi + o_rowTok,
                                                    wsi + o_tokRow);
        gather2_k<<<dim3(cdiv(2 * T_ * 96, 256), 2), blk, 0, stream>>>(hP, wsi + o_rowTok, AgP,
                                                                       PL_TD, PL_AG);
        // expert FFN in 4 groups of 2 experts
        for (int g = 0; g < 4; ++g) {
            transp2_k<<<dim3(64, 24, 2), blk, 0, stream>>>(
                ew1 + ((size_t)i * E_ + 2 * g) * D_ * FF_, eTP, D_, FF_, FF_,
                (size_t)D_ * FF_, EST, PL_E);
            mm2_moe_k<3><<<dim3(16, 33, 2), blk, 0, stream>>>(
                AgP, AgP + PL_AG, eTP, EST, PL_E, eb1 + (size_t)i * E_ * FF_ + 2 * g * FF_, FF_,
                nullptr, h1P, PL_H1, wsi + o_counts + 2 * g, wsi + o_offs + 2 * g,
                FF_, D_, D_, D_, FF_);
        }
        for (int g = 0; g < 4; ++g) {
            transp2_k<<<dim3(24, 64, 2), blk, 0, stream>>>(
                ew2 + ((size_t)i * E_ + 2 * g) * FF_ * D_, eTP, FF_, D_, D_,
                (size_t)FF_ * D_, EST, PL_E);
            mm2_moe_k<0><<<dim3(6, 33, 2), blk, 0, stream>>>(
                h1P, h1P + PL_H1, eTP, EST, PL_E, eb2 + (size_t)i * E_ * D_ + 2 * g * D_, D_,
                ws + o_y2, nullptr, 0, wsi + o_counts + 2 * g, wsi + o_offs + 2 * g,
                D_, FF_, FF_, FF_, D_);
        }
        combine_k<<<cdiv(T_ * D_, 256), blk, 0, stream>>>(ws + o_y2, wsi + o_tokRow, ws + o_tokW,
                                                          ws + o_x, ctxP, PL_TD);
    }

    // ---- output projection -> s pair ----
    transp2_k<<<dim3(36, 24, 1), blk, 0, stream>>>(outw, Wsh, D_, NS2, NPADO, 0, 0, PL_OUTW);
    pad_outb_k<<<cdiv(NPADO, 256), blk, 0, stream>>>(outb, ws + o_obp);
    mm2_k<2><<<dim3(NPADO / 128, 16), blk, 0, stream>>>(ctxP, ctxP + PL_TD, Wsh, Wsh + PL_OUTW,
                                                        ws + o_obp, nullptr, (short*)(ws + o_s),
                                                        PL_S, KPAD, D_, D_, D_, KPAD);
    // ---- ISTFT ----
    basisT2_k<<<cdiv(WIN_ * KPAD, 256), blk, 0, stream>>>((short*)(ws + o_basisT), PL_BAS);
    mm2_k<0><<<dim3(8, 16), blk, 0, stream>>>((short*)(ws + o_s), (short*)(ws + o_s) + PL_S,
                                              (short*)(ws + o_basisT),
                                              (short*)(ws + o_basisT) + PL_BAS, nullptr,
                                              ws + o_frames, nullptr, 0, WIN_, KPAD, KPAD, KPAD,
                                              WIN_);
    ola_k<<<cdiv(out_size, 256), blk, 0, stream>>>(ws + o_frames, (float*)d_out, out_size);
}

// Round 3
// 1771.784 us; speedup vs baseline: 1.5581x; 1.2042x over previous
//
#include <hip/hip_runtime.h>
#include <hip/hip_bf16.h>
#include <math.h>

#define B_    2
#define CIN   512
#define S_    1024
#define D_    768
#define NH    12
#define HD_   64
#define E_    8
#define FF_   2048
#define T_    2048
#define FBINS 513
#define NS2   1026
#define KPAD  1056              // NS2 padded to mult of 32
#define NPADO 1152              // NS2 padded to mult of 128
#define WIN_  1024
#define HOP_  256
#define PAD_  384
#define OUTP  262144
#define AGR   4224              // 2T + 128 pad rows

static inline int cdiv(int a, int b) { return (a + b - 1) / b; }

typedef _Float16 half8 __attribute__((ext_vector_type(8)));
typedef __attribute__((ext_vector_type(4))) float floatx4;

#define MFMA16(a, b, c) __builtin_amdgcn_mfma_f32_16x16x32_f16(a, b, c, 0, 0, 0)
#define LO_SCALE 2048.0f
#define LO_INV   (1.0f / 2048.0f)

// split fp32 -> (hi fp16, lo fp16 scaled by 2048); planes are short-typed
__device__ inline void split_store(float v, short* p, size_t planeOff) {
    _Float16 h = (_Float16)v;
    _Float16 l = (_Float16)((v - (float)h) * LO_SCALE);
    *(_Float16*)p = h;
    *(_Float16*)(p + planeOff) = l;
}

__device__ inline float gelu_f(float x) {
    float x3 = x * x * x;
    return 0.5f * x * (1.0f + tanhf(0.7978845608028654f * (x + 0.044715f * x3)));
}

__device__ inline void gl_lds16(const short* g, short* l) {
    __builtin_amdgcn_global_load_lds((const __attribute__((address_space(1))) void*)g,
                                     (__attribute__((address_space(3))) void*)l, 16, 0, 0);
}

// ===== generic fp32 zero (float4) =====
__global__ __launch_bounds__(256) void zerof_k(float* __restrict__ p, int n4) {
    int i = blockIdx.x * 256 + threadIdx.x;
    if (i < n4) ((float4*)p)[i] = make_float4(0.f, 0.f, 0.f, 0.f);
}

// ===== split-fp16 MFMA GEMM core (128x128 tile, BK=32, 3 MFMAs per frag pair) =====
// Double-buffered: prefetch tile kt+1 before computing kt; ONE barrier per iter.
// Split-K via blockIdx.z (chunk = K/gridDim.z, must be mult of 32).
// MODE 0: f32 store (z=1 only); 1: f32 atomicAdd (bias on chunk 0);
// MODE 2: split-pair store (z=1); 3: gelu -> split-pair store (z=1)
template <int MODE>
__global__ __launch_bounds__(256) void mm2_k(
    const short* __restrict__ Ah, const short* __restrict__ Al,
    const short* __restrict__ Bh, const short* __restrict__ Bl,
    const float* __restrict__ bias, float* __restrict__ Cf,
    short* __restrict__ Cp, size_t CpPl,
    int Nstore, int K, int SA, int SB, int SC) {
    __shared__ short AsH[2][4096], AsL[2][4096], BsH[2][4096], BsL[2][4096];
    int tid = threadIdx.x;
    int wave = tid >> 6, lane = tid & 63;
    int m0 = blockIdx.y * 128, n0 = blockIdx.x * 128;
    int kcz = blockIdx.z;
    int kIters = K >> 5;
    int kcIters = kIters / (int)gridDim.z;
    int ktBase = kcz * kcIters, ktEnd = ktBase + kcIters;
    int wm = (wave & 1) * 64, wn = (wave >> 1) * 64;
    floatx4 a1[4][4], a2[4][4];
#pragma unroll
    for (int i = 0; i < 4; ++i)
#pragma unroll
        for (int j = 0; j < 4; ++j) {
            a1[i][j] = (floatx4){0.f, 0.f, 0.f, 0.f};
            a2[i][j] = (floatx4){0.f, 0.f, 0.f, 0.f};
        }
    int lm = lane & 15, lk = (lane >> 4) * 8;
    int fl0 = wave * 64 + lane, fl1 = fl0 + 256;
    int r0 = fl0 >> 2, c0 = (fl0 & 3) * 8;
    int r1 = fl1 >> 2, c1 = (fl1 & 3) * 8;
    int dst0 = wave * 512, dst1 = (wave + 4) * 512;

    auto stage = [&](int kt, int bb) {
        int k0 = kt << 5;
        size_t a0 = (size_t)(m0 + r0) * SA + k0 + c0;
        size_t a1o = (size_t)(m0 + r1) * SA + k0 + c1;
        size_t b0 = (size_t)(n0 + r0) * SB + k0 + c0;
        size_t b1 = (size_t)(n0 + r1) * SB + k0 + c1;
        gl_lds16(Ah + a0, &AsH[bb][dst0]);
        gl_lds16(Ah + a1o, &AsH[bb][dst1]);
        gl_lds16(Al + a0, &AsL[bb][dst0]);
        gl_lds16(Al + a1o, &AsL[bb][dst1]);
        gl_lds16(Bh + b0, &BsH[bb][dst0]);
        gl_lds16(Bh + b1, &BsH[bb][dst1]);
        gl_lds16(Bl + b0, &BsL[bb][dst0]);
        gl_lds16(Bl + b1, &BsL[bb][dst1]);
    };

    stage(ktBase, 0);
    __syncthreads();
    int cur = 0;
    for (int kt = ktBase; kt < ktEnd; ++kt) {
        if (kt + 1 < ktEnd) stage(kt + 1, cur ^ 1);
        const short* aH = AsH[cur];
        const short* aL = AsL[cur];
        const short* bH = BsH[cur];
        const short* bL = BsL[cur];
        half8 ah[4], al[4], bh[4], bl[4];
#pragma unroll
        for (int i = 0; i < 4; ++i) {
            int off = (wm + i * 16 + lm) * 32 + lk;
            ah[i] = *(const half8*)(aH + off);
            al[i] = *(const half8*)(aL + off);
        }
#pragma unroll
        for (int j = 0; j < 4; ++j) {
            int off = (wn + j * 16 + lm) * 32 + lk;
            bh[j] = *(const half8*)(bH + off);
            bl[j] = *(const half8*)(bL + off);
        }
#pragma unroll
        for (int i = 0; i < 4; ++i)
#pragma unroll
            for (int j = 0; j < 4; ++j) {
                a1[i][j] = MFMA16(ah[i], bh[j], a1[i][j]);
                a2[i][j] = MFMA16(ah[i], bl[j], a2[i][j]);
                a2[i][j] = MFMA16(al[i], bh[j], a2[i][j]);
            }
        __syncthreads();
        cur ^= 1;
    }
    int row4 = (lane >> 4) * 4;
#pragma unroll
    for (int i = 0; i < 4; ++i) {
        int row = m0 + wm + i * 16 + row4;
#pragma unroll
        for (int j = 0; j < 4; ++j) {
            int col = n0 + wn + j * 16 + lm;
            if (col < Nstore) {
                float bv = bias ? bias[col] : 0.0f;
                if (MODE == 1 && kcz != 0) bv = 0.0f;
#pragma unroll
                for (int r = 0; r < 4; ++r) {
                    float v = a1[i][j][r] + a2[i][j][r] * LO_INV + bv;
                    size_t idx = (size_t)(row + r) * SC + col;
                    if (MODE == 0) Cf[idx] = v;
                    else if (MODE == 1) atomicAdd(&Cf[idx], v);
                    else if (MODE == 2) split_store(v, Cp + idx, CpPl);
                    else split_store(gelu_f(v), Cp + idx, CpPl);
                }
            }
        }
    }
}

// ===== grouped MoE variant over expert row-segments (2 experts per launch) =====
// KS = log2(k-split); k-chunk packed in low bits of blockIdx.y.
// MODE 0: f32 atomicAdd (bias on chunk 0); MODE 3: gelu -> split-pair store (KS=0)
template <int MODE, int KS>
__global__ __launch_bounds__(256) void mm2_moe_k(
    const short* __restrict__ Agh, const short* __restrict__ Agl,
    const short* __restrict__ BT, size_t eStride, size_t bPl,
    const float* __restrict__ biasAll, int biasStride,
    float* __restrict__ Cf, short* __restrict__ Cp, size_t CpPl,
    const int* __restrict__ counts, const int* __restrict__ offsets,
    int N, int K, int SA, int SB, int SC) {
    int el = blockIdx.z;
    int nrows = counts[el];
    int kc = blockIdx.y & ((1 << KS) - 1);
    int m0 = (blockIdx.y >> KS) * 128;
    if (m0 >= nrows) return;
    int base = offsets[el];
    const short* Ah = Agh + (size_t)base * SA;
    const short* Al = Agl + (size_t)base * SA;
    const short* Bh = BT + (size_t)el * eStride;
    const short* Bl = Bh + bPl;
    const float* bias = biasAll + (size_t)el * biasStride;
    __shared__ short AsH[2][4096], AsL[2][4096], BsH[2][4096], BsL[2][4096];
    int tid = threadIdx.x;
    int wave = tid >> 6, lane = tid & 63;
    int n0 = blockIdx.x * 128;
    int wm = (wave & 1) * 64, wn = (wave >> 1) * 64;
    int kIters = K >> 5;
    int kcIters = kIters >> KS;
    int ktBase = kc * kcIters, ktEnd = ktBase + kcIters;
    floatx4 a1[4][4], a2[4][4];
#pragma unroll
    for (int i = 0; i < 4; ++i)
#pragma unroll
        for (int j = 0; j < 4; ++j) {
            a1[i][j] = (floatx4){0.f, 0.f, 0.f, 0.f};
            a2[i][j] = (floatx4){0.f, 0.f, 0.f, 0.f};
        }
    int lm = lane & 15, lk = (lane >> 4) * 8;
    int fl0 = wave * 64 + lane, fl1 = fl0 + 256;
    int r0 = fl0 >> 2, c0 = (fl0 & 3) * 8;
    int r1 = fl1 >> 2, c1 = (fl1 & 3) * 8;
    int dst0 = wave * 512, dst1 = (wave + 4) * 512;

    auto stage = [&](int kt, int bb) {
        int k0 = kt << 5;
        size_t a0 = (size_t)(m0 + r0) * SA + k0 + c0;
        size_t a1o = (size_t)(m0 + r1) * SA + k0 + c1;
        size_t b0 = (size_t)(n0 + r0) * SB + k0 + c0;
        size_t b1 = (size_t)(n0 + r1) * SB + k0 + c1;
        gl_lds16(Ah + a0, &AsH[bb][dst0]);
        gl_lds16(Ah + a1o, &AsH[bb][dst1]);
        gl_lds16(Al + a0, &AsL[bb][dst0]);
        gl_lds16(Al + a1o, &AsL[bb][dst1]);
        gl_lds16(Bh + b0, &BsH[bb][dst0]);
        gl_lds16(Bh + b1, &BsH[bb][dst1]);
        gl_lds16(Bl + b0, &BsL[bb][dst0]);
        gl_lds16(Bl + b1, &BsL[bb][dst1]);
    };

    stage(ktBase, 0);
    __syncthreads();
    int cur = 0;
    for (int kt = ktBase; kt < ktEnd; ++kt) {
        if (kt + 1 < ktEnd) stage(kt + 1, cur ^ 1);
        const short* aH = AsH[cur];
        const short* aL = AsL[cur];
        const short* bH = BsH[cur];
        const short* bL = BsL[cur];
        half8 ah[4], al[4], bh[4], bl[4];
#pragma unroll
        for (int i = 0; i < 4; ++i) {
            int off = (wm + i * 16 + lm) * 32 + lk;
            ah[i] = *(const half8*)(aH + off);
            al[i] = *(const half8*)(aL + off);
        }
#pragma unroll
        for (int j = 0; j < 4; ++j) {
            int off = (wn + j * 16 + lm) * 32 + lk;
            bh[j] = *(const half8*)(bH + off);
            bl[j] = *(const half8*)(bL + off);
        }
#pragma unroll
        for (int i = 0; i < 4; ++i)
#pragma unroll
            for (int j = 0; j < 4; ++j) {
                a1[i][j] = MFMA16(ah[i], bh[j], a1[i][j]);
                a2[i][j] = MFMA16(ah[i], bl[j], a2[i][j]);
                a2[i][j] = MFMA16(al[i], bh[j], a2[i][j]);
            }
        __syncthreads();
        cur ^= 1;
    }
    int row4 = (lane >> 4) * 4;
#pragma unroll
    for (int i = 0; i < 4; ++i) {
        int rl = m0 + wm + i * 16 + row4;
#pragma unroll
        for (int j = 0; j < 4; ++j) {
            int col = n0 + wn + j * 16 + lm;
            if (col < N) {
                float bv = bias[col];
                if (MODE == 0 && kc != 0) bv = 0.0f;
#pragma unroll
                for (int r = 0; r < 4; ++r) {
                    if (rl + r < nrows) {
                        float v = a1[i][j][r] + a2[i][j][r] * LO_INV + bv;
                        size_t idx = (size_t)(base + rl + r) * SC + col;
                        if (MODE == 0) atomicAdd(&Cf[idx], v);
                        else split_store(gelu_f(v), Cp + idx, CpPl);
                    }
                }
            }
        }
    }
}

// ===== transpose fp32 [Z][R][C] -> split-pair [Z][Cout][R] (zero rows c>=C) =====
__global__ __launch_bounds__(256) void transp2_k(const float* __restrict__ src,
                                                 short* __restrict__ dst, int R, int C, int Cout,
                                                 size_t srcZ, size_t dstZ, size_t planeOff) {
    __shared__ float tile[32][33];
    int z = blockIdx.z;
    src += (size_t)z * srcZ;
    dst += (size_t)z * dstZ;
    int c0 = blockIdx.x * 32, r0 = blockIdx.y * 32;
    int tx = threadIdx.x & 31, ty = threadIdx.x >> 5;
    for (int i = ty; i < 32; i += 8) {
        int r = r0 + i, c = c0 + tx;
        tile[i][tx] = (r < R && c < C) ? src[(size_t)r * C + c] : 0.0f;
    }
    __syncthreads();
    for (int i = ty; i < 32; i += 8) {
        int cc = c0 + i, rr = r0 + tx;
        if (cc < Cout && rr < R) split_store(tile[tx][i], dst + (size_t)cc * R + rr, planeOff);
    }
}

// ===== transpose z: [B,CIN,S] -> zT pair [t][c] =====
__global__ __launch_bounds__(256) void tz2_k(const float* __restrict__ z, short* __restrict__ xT,
                                             size_t planeOff) {
    int id = blockIdx.x * 256 + threadIdx.x;
    if (id >= T_ * CIN) return;
    int t = id >> 9, c = id & 511;
    int b = t >> 10, l = t & 1023;
    split_store(z[((size_t)b * CIN + c) * S_ + l], xT + id, planeOff);
}

// ===== LayerNorm per token -> split pair =====
__global__ __launch_bounds__(256) void ln_k(const float* __restrict__ x,
                                            const float* __restrict__ g,
                                            const float* __restrict__ b, short* __restrict__ h,
                                            size_t planeOff) {
    int t = blockIdx.x;
    int tid = threadIdx.x;
    __shared__ float row[D_];
    __shared__ float red[256];
    const float* xr = x + (size_t)t * D_;
    float s = 0.0f;
    for (int i = tid; i < D_; i += 256) {
        float v = xr[i];
        row[i] = v;
        s += v;
    }
    red[tid] = s;
    __syncthreads();
    for (int st = 128; st > 0; st >>= 1) {
        if (tid < st) red[tid] += red[tid + st];
        __syncthreads();
    }
    float mean = red[0] / (float)D_;
    __syncthreads();
    float s2 = 0.0f;
    for (int i = tid; i < D_; i += 256) {
        float d = row[i] - mean;
        s2 += d * d;
    }
    red[tid] = s2;
    __syncthreads();
    for (int st = 128; st > 0; st >>= 1) {
        if (tid < st) red[tid] += red[tid + st];
        __syncthreads();
    }
    float rstd = rsqrtf(red[0] / (float)D_ + 1e-5f);
    for (int i = tid; i < D_; i += 256)
        split_store((row[i] - mean) * rstd * g[i] + b[i], h + (size_t)t * D_ + i, planeOff);
}

// ===== fused fp32 LN + gating logits =====
__global__ __launch_bounds__(256) void lngate_k(const float* __restrict__ x,
                                                const float* __restrict__ g,
                                                const float* __restrict__ b,
                                                const float* __restrict__ gw,
                                                float* __restrict__ logits) {
    int t = blockIdx.x;
    int tid = threadIdx.x;
    __shared__ float row[D_];
    __shared__ float red[256];
    const float* xr = x + (size_t)t * D_;
    float s = 0.0f;
    for (int i = tid; i < D_; i += 256) {
        float v = xr[i];
        row[i] = v;
        s += v;
    }
    red[tid] = s;
    __syncthreads();
    for (int st = 128; st > 0; st >>= 1) {
        if (tid < st) red[tid] += red[tid + st];
        __syncthreads();
    }
    float mean = red[0] / (float)D_;
    __syncthreads();
    float s2 = 0.0f;
    for (int i = tid; i < D_; i += 256) {
        float d = row[i] - mean;
        s2 += d * d;
    }
    red[tid] = s2;
    __syncthreads();
    for (int st = 128; st > 0; st >>= 1) {
        if (tid < st) red[tid] += red[tid + st];
        __syncthreads();
    }
    float rstd = rsqrtf(red[0] / (float)D_ + 1e-5f);
    __syncthreads();
    int e = tid >> 5, lane = tid & 31;
    float acc = 0.0f;
    for (int d = lane; d < D_; d += 32)
        acc += ((row[d] - mean) * rstd * g[d] + b[d]) * gw[d * E_ + e];
    red[tid] = acc;
    __syncthreads();
    for (int st = 16; st > 0; st >>= 1) {
        if (lane < st) red[tid] += red[tid + st];
        __syncthreads();
    }
    if (lane == 0) logits[t * E_ + e] = red[tid];
}

// ===== concat 3 bias vectors [768] -> [2304] =====
__global__ void catb_k(const float* __restrict__ a, const float* __restrict__ b,
                       const float* __restrict__ c, float* __restrict__ dst) {
    int i = blockIdx.x * 256 + threadIdx.x;
    if (i < 768) dst[i] = a[i];
    else if (i < 1536) dst[i] = b[i - 768];
    else if (i < 2304) dst[i] = c[i - 1536];
}

// ===== RoPE on fused qkv [T][2304] (cols 0..767=q, 768..1535=k) -> split pairs =====
__global__ __launch_bounds__(256) void ropesplit_k(const float* __restrict__ qkv,
                                                   short* __restrict__ qd,
                                                   short* __restrict__ kd) {
    int id = blockIdx.x * 256 + threadIdx.x;
    if (id >= T_ * 384) return;
    int t = id / 384, j = id % 384;
    int pos = t & 1023;
    float inv = expf(-(float)j * (9.210340371976184f / 384.0f));
    float ang = (float)pos * inv;
    float sn, cs;
    sincosf(ang, &sn, &cs);
    const float* pq = qkv + (size_t)t * 2304 + 2 * j;
    const float* pk = pq + 768;
    const size_t PL = (size_t)T_ * D_;
    size_t o = (size_t)t * D_ + 2 * j;
    float q1 = pq[0], q2 = pq[1];
    split_store(q1 * cs - q2 * sn, qd + o, PL);
    split_store(q1 * sn + q2 * cs, qd + o + 1, PL);
    float k1 = pk[0], k2 = pk[1];
    split_store(k1 * cs - k2 * sn, kd + o, PL);
    split_store(k1 * sn + k2 * cs, kd + o + 1, PL);
}

// ===== q,k columns of fused qkv -> split pairs (no rope) =====
__global__ __launch_bounds__(256) void qksplit_k(const float* __restrict__ qkv,
                                                 short* __restrict__ qd,
                                                 short* __restrict__ kd) {
    int id = blockIdx.x * 256 + threadIdx.x;
    if (id >= T_ * D_) return;
    int t = id / D_, c = id % D_;
    const size_t PL = (size_t)T_ * D_;
    split_store(qkv[(size_t)t * 2304 + c], qd + id, PL);
    split_store(qkv[(size_t)t * 2304 + 768 + c], kd + id, PL);
}

// ===== V cols of fused qkv [T][2304] -> V^T pair [BH][64][S] =====
__global__ __launch_bounds__(256) void vt2_k(const float* __restrict__ qkv,
                                             short* __restrict__ vp) {
    __shared__ float tile[32][33];
    int bh = blockIdx.z, b = bh / NH, h = bh % NH;
    int j0 = blockIdx.x * 32, d0 = blockIdx.y * 32;
    int tx = threadIdx.x & 31, ty = threadIdx.x >> 5;
    for (int i = ty; i < 32; i += 8)
        tile[i][tx] = qkv[(size_t)(b * S_ + j0 + i) * 2304 + 1536 + h * 64 + d0 + tx];
    __syncthreads();
    for (int i = ty; i < 32; i += 8)
        split_store(tile[tx][i], vp + ((size_t)bh * 64 + d0 + i) * S_ + j0 + tx,
                    (size_t)T_ * D_);
}

// ===== flash attention: split-fp16 MFMA, online softmax, causal =====
// grid (8 balanced q-tile pairs, 24 bh), block 256 (4 waves x 16 Q-rows).
// Each block handles q-tiles {qp, 15-qp}: 9 kv-iterations each -> perfect balance.
// LDS tiles use a slot^(row&7) XOR swizzle (16B granularity) to reach the 8-round
// b128 minimum: staging pre-swizzles the GLOBAL source column (gl_lds dest linear).
__global__ __launch_bounds__(256) void fattn_k(const short* __restrict__ qp,
                                               const short* __restrict__ kp,
                                               const short* __restrict__ vp,
                                               short* __restrict__ ctx) {
    __shared__ short sQ[2][64 * 64];
    __shared__ short sK[2][128 * 64];
    __shared__ short sV[2][64 * 128];
    __shared__ short sP[2][4][16 * 128];
    const size_t PL = (size_t)T_ * D_;
    int qpair = blockIdx.x, bh = blockIdx.y;
    int b = bh / NH, h = bh % NH;
    int tid = threadIdx.x, wave = tid >> 6, lane = tid & 63;
    int quad = lane >> 4, lm = lane & 15;
    int lr8 = lane >> 3;                         // row-in-8-chunk for 64-short rows
    int lc8 = ((lane & 7) ^ lr8) * 8;            // pre-swizzled source col (64-short rows)
    int lm7 = lm & 7;                            // read-side row&7 (rows = base + lm)

    for (int hh = 0; hh < 2; ++hh) {
        int qt = hh ? (15 - qpair) : qpair;
        int t0 = b * S_ + qt * 64;
        {   // stage Q: per wave, 2 chunks of 8 rows per plane (swizzled source)
#pragma unroll
            for (int pl = 0; pl < 2; ++pl)
#pragma unroll
                for (int c = 0; c < 2; ++c) {
                    int r8 = wave * 16 + c * 8;
                    gl_lds16(qp + pl * PL + (size_t)(t0 + r8 + lr8) * D_ + h * 64 + lc8,
                             &sQ[pl][r8 * 64]);
                }
        }
        floatx4 o1[4], o2[4];
#pragma unroll
        for (int n = 0; n < 4; ++n) {
            o1[n] = (floatx4){0.f, 0.f, 0.f, 0.f};
            o2[n] = (floatx4){0.f, 0.f, 0.f, 0.f};
        }
        float mrow[4] = {-1e30f, -1e30f, -1e30f, -1e30f};
        float lrow[4] = {0.f, 0.f, 0.f, 0.f};
        int ktmax = qt >> 1;
        for (int kt = 0; kt <= ktmax; ++kt) {
            {   // stage K: per wave, 4 chunks of 8 rows per plane (swizzled source)
#pragma unroll
                for (int pl = 0; pl < 2; ++pl)
#pragma unroll
                    for (int c = 0; c < 4; ++c) {
                        int r8 = wave * 32 + c * 8;
                        gl_lds16(kp + pl * PL +
                                     (size_t)(b * S_ + kt * 128 + r8 + lr8) * D_ + h * 64 + lc8,
                                 &sK[pl][r8 * 64]);
                    }
                // stage V^T: per wave, 4 chunks of 4 rows (128-short rows, swizzled source)
                int vr = lane >> 4;
#pragma unroll
                for (int pl = 0; pl < 2; ++pl)
#pragma unroll
                    for (int c = 0; c < 4; ++c) {
                        int r4 = wave * 16 + c * 4;
                        int vcs = (((lane & 15) ^ (((c & 1) << 2) + vr))) * 8;
                        gl_lds16(vp + pl * PL + ((size_t)bh * 64 + r4 + vr) * S_ + kt * 128 + vcs,
                                 &sV[pl][r4 * 128]);
                    }
            }
            __syncthreads();
            // ---- S = Q K^T * scale (split-fp16) ----
            half8 qh[2], ql[2];
#pragma unroll
            for (int ks = 0; ks < 2; ++ks) {
                int off = (wave * 16 + lm) * 64 + ((ks * 4 + quad) ^ lm7) * 8;
                qh[ks] = *(const half8*)&sQ[0][off];
                ql[ks] = *(const half8*)&sQ[1][off];
            }
            floatx4 sacc[8];
#pragma unroll
            for (int nt = 0; nt < 8; ++nt) {
                floatx4 c1 = (floatx4){0.f, 0.f, 0.f, 0.f};
                floatx4 c2 = (floatx4){0.f, 0.f, 0.f, 0.f};
#pragma unroll
                for (int ks = 0; ks < 2; ++ks) {
                    int off = (nt * 16 + lm) * 64 + ((ks * 4 + quad) ^ lm7) * 8;
                    half8 kh = *(const half8*)&sK[0][off];
                    half8 kl = *(const half8*)&sK[1][off];
                    c1 = MFMA16(qh[ks], kh, c1);
                    c2 = MFMA16(qh[ks], kl, c2);
                    c2 = MFMA16(ql[ks], kh, c2);
                }
#pragma unroll
                for (int r = 0; r < 4; ++r) sacc[nt][r] = (c1[r] + c2[r] * LO_INV) * 0.125f;
            }
            if (kt == ktmax) {  // causal mask on the diagonal tile
#pragma unroll
                for (int nt = 0; nt < 8; ++nt) {
                    int col = kt * 128 + nt * 16 + lm;
#pragma unroll
                    for (int r = 0; r < 4; ++r) {
                        int rowg = qt * 64 + wave * 16 + quad * 4 + r;
                        if (col > rowg) sacc[nt][r] = -1e30f;
                    }
                }
            }
            // ---- online softmax (wave-local; rows live in 16-lane quads) ----
            float mnew[4], al[4], ls[4];
#pragma unroll
            for (int r = 0; r < 4; ++r) {
                float mx = sacc[0][r];
#pragma unroll
                for (int nt = 1; nt < 8; ++nt) mx = fmaxf(mx, sacc[nt][r]);
#pragma unroll
                for (int msk = 1; msk < 16; msk <<= 1) mx = fmaxf(mx, __shfl_xor(mx, msk));
                mnew[r] = fmaxf(mrow[r], mx);
                al[r] = __expf(mrow[r] - mnew[r]);
                mrow[r] = mnew[r];
                ls[r] = 0.f;
            }
#pragma unroll
            for (int nt = 0; nt < 8; ++nt)
#pragma unroll
                for (int r = 0; r < 4; ++r) {
                    float p = __expf(sacc[nt][r] - mnew[r]);
                    ls[r] += p;
                    _Float16 ph = (_Float16)p;
                    _Float16 plo = (_Float16)((p - (float)ph) * LO_SCALE);
                    int rowp = quad * 4 + r;
                    int off = rowp * 128 + ((nt * 2 + (lm >> 3)) ^ (rowp & 7)) * 8 + (lm & 7);
                    *(_Float16*)&sP[0][wave][off] = ph;
                    *(_Float16*)&sP[1][wave][off] = plo;
                }
#pragma unroll
            for (int r = 0; r < 4; ++r) {
#pragma unroll
                for (int msk = 1; msk < 16; msk <<= 1) ls[r] += __shfl_xor(ls[r], msk);
                lrow[r] = lrow[r] * al[r] + ls[r];
            }
#pragma unroll
            for (int n = 0; n < 4; ++n)
#pragma unroll
                for (int r = 0; r < 4; ++r) {
                    o1[n][r] *= al[r];
                    o2[n][r] *= al[r];
                }
            // ---- O += P V (split-fp16; P via per-wave LDS roundtrip) ----
            half8 ph8[4], pl8[4];
#pragma unroll
            for (int ks = 0; ks < 4; ++ks) {
                int off = lm * 128 + ((ks * 4 + quad) ^ lm7) * 8;
                ph8[ks] = *(const half8*)&sP[0][wave][off];
                pl8[ks] = *(const half8*)&sP[1][wave][off];
            }
#pragma unroll
            for (int nt2 = 0; nt2 < 4; ++nt2) {
#pragma unroll
                for (int ks = 0; ks < 4; ++ks) {
                    int off = (nt2 * 16 + lm) * 128 + ((ks * 4 + quad) ^ lm7) * 8;
                    half8 vh = *(const half8*)&sV[0][off];
                    half8 vl = *(const half8*)&sV[1][off];
                    o1[nt2] = MFMA16(ph8[ks], vh, o1[nt2]);
                    o2[nt2] = MFMA16(ph8[ks], vl, o2[nt2]);
                    o2[nt2] = MFMA16(pl8[ks], vh, o2[nt2]);
                }
            }
            __syncthreads();
        }
        // ---- epilogue: normalize, split-store ctx ----
#pragma unroll
        for (int r = 0; r < 4; ++r) {
            float inv = 1.0f / lrow[r];
            int rowg = t0 + wave * 16 + quad * 4 + r;
#pragma unroll
            for (int nt2 = 0; nt2 < 4; ++nt2) {
                float val = (o1[nt2][r] + o2[nt2][r] * LO_INV) * inv;
                int col = h * 64 + nt2 * 16 + lm;
                split_store(val, ctx + (size_t)rowg * D_ + col, PL);
            }
        }
    }
}

__global__ void zero_meta_k(int* __restrict__ counts) {
    int i = threadIdx.x;
    if (i < E_) counts[i] = 0;
}

__global__ __launch_bounds__(256) void top2_k(const float* __restrict__ logits,
                                              int* __restrict__ counts, int* __restrict__ tokE,
                                              float* __restrict__ tokW) {
    int t = blockIdx.x * 256 + threadIdx.x;
    if (t >= T_) return;
    const float* l = logits + t * E_;
    int i0 = 0;
    float v0 = l[0];
    for (int e = 1; e < E_; ++e) {
        float v = l[e];
        if (v > v0) { v0 = v; i0 = e; }
    }
    int i1 = -1;
    float v1 = -1e30f;
    for (int e = 0; e < E_; ++e) {
        if (e == i0) continue;
        float v = l[e];
        if (v > v1) { v1 = v; i1 = e; }
    }
    float e2 = expf(v1 - v0);
    float w0 = 1.0f / (1.0f + e2);
    float w1 = e2 * w0;
    tokE[2 * t] = i0;
    tokE[2 * t + 1] = i1;
    tokW[2 * t] = w0;
    tokW[2 * t + 1] = w1;
    atomicAdd(&counts[i0], 1);
    atomicAdd(&counts[i1], 1);
}

__global__ void offsets_k(const int* __restrict__ counts, int* __restrict__ offsets,
                          int* __restrict__ cursor) {
    if (threadIdx.x == 0 && blockIdx.x == 0) {
        int a = 0;
        for (int e = 0; e < E_; ++e) {
            offsets[e] = a;
            cursor[e] = a;
            a += counts[e];
        }
    }
}

__global__ __launch_bounds__(256) void assign_k(const int* __restrict__ tokE,
                                                int* __restrict__ cursor,
                                                int* __restrict__ rowTok,
                                                int* __restrict__ tokRow) {
    int t = blockIdx.x * 256 + threadIdx.x;
    if (t >= T_) return;
    for (int s = 0; s < 2; ++s) {
        int e = tokE[2 * t + s];
        int r = atomicAdd(&cursor[e], 1);
        rowTok[r] = t;
        tokRow[2 * t + s] = r;
    }
}

// gather pair rows: Ag[p][r][:] = h[p][rowTok[r]][:]
__global__ __launch_bounds__(256) void gather2_k(const short* __restrict__ h,
                                                 const int* __restrict__ rowTok,
                                                 short* __restrict__ Ag, size_t hPl, size_t aPl) {
    int id = blockIdx.x * 256 + threadIdx.x;  // r*96 + c (uint4 units)
    if (id >= 2 * T_ * 96) return;
    int p = blockIdx.y;
    int r = id / 96, c = id % 96;
    const uint4* src = (const uint4*)(h + p * hPl) + (size_t)rowTok[r] * 96 + c;
    ((uint4*)(Ag + p * aPl))[(size_t)r * 96 + c] = *src;
}

__global__ __launch_bounds__(256) void combine_k(const float* __restrict__ y2,
                                                 const int* __restrict__ tokRow,
                                                 const float* __restrict__ tokW,
                                                 float* __restrict__ x, short* __restrict__ xb,
                                                 size_t xbPl) {
    int id = blockIdx.x * 256 + threadIdx.x;
    if (id >= T_ * D_) return;
    int t = id / D_;
    float v = x[id] + tokW[2 * t] * y2[(size_t)tokRow[2 * t] * D_ + id % D_] +
              tokW[2 * t + 1] * y2[(size_t)tokRow[2 * t + 1] * D_ + id % D_];
    x[id] = v;
    split_store(v, xb + id, xbPl);
}

__global__ void pad_outb_k(const float* __restrict__ outb, float* __restrict__ obp) {
    int i = blockIdx.x * 256 + threadIdx.x;
    if (i < NPADO) obp[i] = (i < NS2) ? outb[i] : 0.0f;
}

// basisT pair [n][j], stride KPAD; j>=NS2 -> 0
__global__ __launch_bounds__(256) void basisT2_k(short* __restrict__ bT, size_t planeOff) {
    int id = blockIdx.x * 256 + threadIdx.x;
    if (id >= WIN_ * KPAD) return;
    int n = id / KPAD, j = id % KPAD;
    float val = 0.0f;
    if (j < NS2) {
        float wn = 0.5f - 0.5f * cosf(6.283185307179586f * (float)n / 1024.0f);
        int kf = (j < FBINS) ? j : (j - FBINS);
        float scale = (kf == 0 || kf == 512) ? (1.0f / 1024.0f) : (2.0f / 1024.0f);
        int m = (kf * n) & 1023;
        float th = 6.283185307179586f * (float)m / 1024.0f;
        if (j < FBINS) val = scale * cosf(th);
        else val = (kf == 0 || kf == 512) ? 0.0f : (-scale * sinf(th));
        val *= wn;
    }
    split_store(val, bT + id, planeOff);
}

__global__ __launch_bounds__(256) void ola_k(const float* __restrict__ frames,
                                             float* __restrict__ out, int total) {
    int id = blockIdx.x * 256 + threadIdx.x;
    if (id >= total) return;
    int b = id / OUTP, pout = id % OUTP;
    int p = pout + PAD_;
    int t1 = p >> 8;
    if (t1 > S_ - 1) t1 = S_ - 1;
    int t0 = p - (WIN_ - 1) + (HOP_ - 1);
    t0 = (t0 > 0) ? (t0 >> 8) : 0;
    float acc = 0.0f, env = 0.0f;
    for (int t = t0; t <= t1; ++t) {
        int n = p - (t << 8);
        float wn = 0.5f - 0.5f * cosf(6.283185307179586f * (float)n / 1024.0f);
        acc += frames[(((size_t)(b * S_ + t)) << 10) + n];
        env += wn * wn;
    }
    out[id] = acc / env;
}

// ======================= launcher =======================
extern "C" void kernel_launch(void* const* d_in, const int* in_sizes, int n_in, void* d_out,
                              int out_size, void* d_ws, size_t ws_size, hipStream_t stream) {
    const float* z    = (const float*)d_in[0];
    const float* in_w = (const float*)d_in[1];
    const float* in_b = (const float*)d_in[2];
    const float* ln1g = (const float*)d_in[3];
    const float* ln1b = (const float*)d_in[4];
    const float* wq   = (const float*)d_in[5];
    const float* bq   = (const float*)d_in[6];
    const float* wk   = (const float*)d_in[7];
    const float* bk   = (const float*)d_in[8];
    const float* wv   = (const float*)d_in[9];
    const float* bv   = (const float*)d_in[10];
    const float* wo   = (const float*)d_in[11];
    const float* bo   = (const float*)d_in[12];
    const float* ln2g = (const float*)d_in[13];
    const float* ln2b = (const float*)d_in[14];
    const float* gw   = (const float*)d_in[15];
    const float* ew1  = (const float*)d_in[16];
    const float* eb1  = (const float*)d_in[17];
    const float* ew2  = (const float*)d_in[18];
    const float* eb2  = (const float*)d_in[19];
    const float* outw = (const float*)d_in[20];
    const float* outb = (const float*)d_in[21];

    float* ws = (float*)d_ws;
    int* wsi = (int*)d_ws;
    const size_t TD = (size_t)T_ * D_;
    const size_t o_x      = 0;
    const size_t o_logits = TD;
    const size_t o_counts = o_logits + (size_t)T_ * E_;
    const size_t o_cursor = o_counts + 16;
    const size_t o_offs   = o_cursor + 16;
    const size_t o_tokE   = o_offs + 16;
    const size_t o_rowTok = o_tokE + 2 * T_;
    const size_t o_tokRow = o_rowTok + 2 * T_;
    const size_t o_tokW   = o_tokRow + 2 * T_;
    const size_t o_obp    = o_tokW + 2 * T_;
    const size_t o_W      = ((o_obp + NPADO + 127) / 128) * 128;
    const size_t WSLOT    = (size_t)D_ * D_;
    const size_t o_q      = o_W + 4 * WSLOT;
    const size_t o_k      = o_q + TD;
    const size_t o_v      = o_k + TD;
    const size_t o_h      = o_v + TD;
    const size_t o_ctx    = o_h + TD;
    const size_t o_eT     = o_ctx + TD;
    const size_t o_Ag     = o_eT + 2 * (size_t)FF_ * D_;
    const size_t AgF      = (size_t)AGR * D_;
    const size_t total    = o_Ag + AgF;
    if (ws_size < total * sizeof(float)) return;
    // overlays (phase-disjoint)
    const size_t o_h1     = o_W;
    const size_t o_y2     = o_Ag;
    const size_t o_zT     = o_eT;
    const size_t o_s      = o_eT;
    const size_t o_basisT = o_s + (size_t)T_ * KPAD;
    const size_t o_frames = o_basisT + (size_t)WIN_ * KPAD;
    const size_t o_qp     = o_eT;            // attn pair buffers overlay MoE region
    const size_t o_kp     = o_eT + TD;
    const size_t o_vp     = o_eT + 2 * TD;
    // plane offsets (shorts)
    const size_t PL_TD   = TD;
    const size_t PL_W    = (size_t)D_ * D_;
    const size_t PL_INW  = (size_t)D_ * CIN;
    const size_t PL_OUTW = (size_t)NPADO * D_;
    const size_t PL_E    = (size_t)FF_ * D_;
    const size_t EST     = 2 * PL_E;
    const size_t PL_AG   = (size_t)AGR * D_;
    const size_t PL_H1   = (size_t)AGR * FF_;
    const size_t PL_ZT   = (size_t)T_ * CIN;
    const size_t PL_S    = (size_t)T_ * KPAD;
    const size_t PL_BAS  = (size_t)WIN_ * KPAD;

    dim3 blk(256);
    short* Wsh  = (short*)(ws + o_W);
    short* hP   = (short*)(ws + o_h);
    short* ctxP = (short*)(ws + o_ctx);
    short* eTP  = (short*)(ws + o_eT);
    short* AgP  = (short*)(ws + o_Ag);
    short* h1P  = (short*)(ws + o_h1);
    short* qpP  = (short*)(ws + o_qp);
    short* kpP  = (short*)(ws + o_kp);
    short* vpP  = (short*)(ws + o_vp);

    // ---- in projection (split-K x2, atomic into zeroed x) ----
    tz2_k<<<cdiv(T_ * CIN, 256), blk, 0, stream>>>(z, (short*)(ws + o_zT), PL_ZT);
    transp2_k<<<dim3(24, 16, 1), blk, 0, stream>>>(in_w, Wsh, CIN, D_, D_, 0, 0, PL_INW);
    zerof_k<<<cdiv((int)(TD / 4), 256), blk, 0, stream>>>(ws + o_x, (int)(TD / 4));
    mm2_k<1><<<dim3(6, 16, 2), blk, 0, stream>>>((short*)(ws + o_zT), (short*)(ws + o_zT) + PL_ZT,
                                                 Wsh, Wsh + PL_INW, in_b, ws + o_x, nullptr, 0,
                                                 D_, CIN, CIN, CIN, D_);

    for (int i = 0; i < 2; ++i) {
        const size_t wOff = (size_t)i * D_ * D_;
        const size_t bOff = (size_t)i * D_;
        // fused QKV B^T: hi planes [q|k|v] then lo planes [q|k|v]
        transp2_k<<<dim3(24, 24, 1), blk, 0, stream>>>(wq + wOff, Wsh, D_, D_, D_, 0, 0, 3 * PL_W);
        transp2_k<<<dim3(24, 24, 1), blk, 0, stream>>>(wk + wOff, Wsh + PL_W, D_, D_, D_, 0, 0, 3 * PL_W);
        transp2_k<<<dim3(24, 24, 1), blk, 0, stream>>>(wv + wOff, Wsh + 2 * PL_W, D_, D_, D_, 0, 0, 3 * PL_W);
        transp2_k<<<dim3(24, 24, 1), blk, 0, stream>>>(wo + wOff, Wsh + 6 * PL_W, D_, D_, D_, 0, 0, PL_W);
        catb_k<<<cdiv(2304, 256), blk, 0, stream>>>(bq + bOff, bk + bOff, bv + bOff,
                                                    ws + o_logits);

        ln_k<<<T_, blk, 0, stream>>>(ws + o_x, ln1g + bOff, ln1b + bOff, hP, PL_TD);
        // fused QKV GEMM: [T][768] x [2304][768]^T -> [T][2304] (q|k|v per row)
        mm2_k<0><<<dim3(18, 16), blk, 0, stream>>>(hP, hP + PL_TD, Wsh, Wsh + 3 * PL_W,
                                                   ws + o_logits, ws + o_q, nullptr, 0,
                                                   2304, D_, D_, D_, 2304);
        if (i == 0) {
            ropesplit_k<<<cdiv(T_ * 384, 256), blk, 0, stream>>>(ws + o_q, qpP, kpP);
        } else {
            qksplit_k<<<cdiv(T_ * D_, 256), blk, 0, stream>>>(ws + o_q, qpP, kpP);
        }
        vt2_k<<<dim3(32, 2, B_ * NH), blk, 0, stream>>>(ws + o_q, vpP);
        // flash attention (balanced q-tile pairs)
        fattn_k<<<dim3(8, B_ * NH), blk, 0, stream>>>(qpP, kpP, vpP, ctxP);
        // O-proj: split-K x4, atomic accumulate into live x (bias on chunk 0)
        mm2_k<1><<<dim3(6, 16, 4), blk, 0, stream>>>(ctxP, ctxP + PL_TD, Wsh + 6 * PL_W,
                                                     Wsh + 7 * PL_W, bo + bOff, ws + o_x,
                                                     nullptr, 0, D_, D_, D_, D_, D_);
        // LN2 pair for FFN input + fused fp32 LN+gate for routing
        ln_k<<<T_, blk, 0, stream>>>(ws + o_x, ln2g + bOff, ln2b + bOff, hP, PL_TD);
        lngate_k<<<T_, blk, 0, stream>>>(ws + o_x, ln2g + bOff, ln2b + bOff,
                                         gw + (size_t)i * D_ * E_, ws + o_logits);
        zero_meta_k<<<1, 64, 0, stream>>>(wsi + o_counts);
        top2_k<<<cdiv(T_, 256), blk, 0, stream>>>(ws + o_logits, wsi + o_counts, wsi + o_tokE,
                                                  ws + o_tokW);
        offsets_k<<<1, 64, 0, stream>>>(wsi + o_counts, wsi + o_offs, wsi + o_cursor);
        assign_k<<<cdiv(T_, 256), blk, 0, stream>>>(wsi + o_tokE, wsi + o_cursor, wsi + o_rowTok,
                                                    wsi + o_tokRow);
        gather2_k<<<dim3(cdiv(2 * T_ * 96, 256), 2), blk, 0, stream>>>(hP, wsi + o_rowTok, AgP,
                                                                       PL_TD, PL_AG);
        // expert FFN1 in 4 groups of 2 experts (gelu epilogue, no k-split)
        for (int g = 0; g < 4; ++g) {
            transp2_k<<<dim3(64, 24, 2), blk, 0, stream>>>(
                ew1 + ((size_t)i * E_ + 2 * g) * D_ * FF_, eTP, D_, FF_, FF_,
                (size_t)D_ * FF_, EST, PL_E);
            mm2_moe_k<3, 0><<<dim3(16, 33, 2), blk, 0, stream>>>(
                AgP, AgP + PL_AG, eTP, EST, PL_E, eb1 + (size_t)i * E_ * FF_ + 2 * g * FF_, FF_,
                nullptr, h1P, PL_H1, wsi + o_counts + 2 * g, wsi + o_offs + 2 * g,
                FF_, D_, D_, D_, FF_);
        }
        // FFN2: zero y2, then 4 groups with split-K x4 (atomic accumulate)
        zerof_k<<<cdiv(4096 * D_ / 4, 256), blk, 0, stream>>>(ws + o_y2, 4096 * D_ / 4);
        for (int g = 0; g < 4; ++g) {
            transp2_k<<<dim3(24, 64, 2), blk, 0, stream>>>(
                ew2 + ((size_t)i * E_ + 2 * g) * FF_ * D_, eTP, FF_, D_, D_,
                (size_t)FF_ * D_, EST, PL_E);
            mm2_moe_k<0, 2><<<dim3(6, 132, 2), blk, 0, stream>>>(
                h1P, h1P + PL_H1, eTP, EST, PL_E, eb2 + (size_t)i * E_ * D_ + 2 * g * D_, D_,
                ws + o_y2, nullptr, 0, wsi + o_counts + 2 * g, wsi + o_offs + 2 * g,
                D_, FF_, FF_, FF_, D_);
        }
        combine_k<<<cdiv(T_ * D_, 256), blk, 0, stream>>>(ws + o_y2, wsi + o_tokRow, ws + o_tokW,
                                                          ws + o_x, ctxP, PL_TD);
    }

    // ---- output projection -> s pair ----
    transp2_k<<<dim3(36, 24, 1), blk, 0, stream>>>(outw, Wsh, D_, NS2, NPADO, 0, 0, PL_OUTW);
    pad_outb_k<<<cdiv(NPADO, 256), blk, 0, stream>>>(outb, ws + o_obp);
    mm2_k<2><<<dim3(NPADO / 128, 16), blk, 0, stream>>>(ctxP, ctxP + PL_TD, Wsh, Wsh + PL_OUTW,
                                                        ws + o_obp, nullptr, (short*)(ws + o_s),
                                                        PL_S, KPAD, D_, D_, D_, KPAD);
    // ---- ISTFT (frames GEMM split-K x3 into zeroed frames) ----
    basisT2_k<<<cdiv(WIN_ * KPAD, 256), blk, 0, stream>>>((short*)(ws + o_basisT), PL_BAS);
    zerof_k<<<cdiv((int)(B_ * S_ * WIN_ / 4), 256), blk, 0, stream>>>(ws + o_frames,
                                                                      B_ * S_ * WIN_ / 4);
    mm2_k<1><<<dim3(8, 16, 3), blk, 0, stream>>>((short*)(ws + o_s), (short*)(ws + o_s) + PL_S,
                                                 (short*)(ws + o_basisT),
                                                 (short*)(ws + o_basisT) + PL_BAS, nullptr,
                                                 ws + o_frames, nullptr, 0, WIN_, KPAD, KPAD, KPAD,
                                                 WIN_);
    ola_k<<<cdiv(out_size, 256), blk, 0, stream>>>(ws + o_frames, (float*)d_out, out_size);
}